// Round 2
// baseline (1565.708 us; speedup 1.0000x reference)
//
#include <hip/hip_runtime.h>

#define N_NODES 50000
#define E_EDGES 800000
#define FEAT    128
#define KORD    3
#define BN_EPS  1e-5f

// ---- ordered-uint encoding for float atomicMax (order-independent) ----
__device__ __forceinline__ unsigned f2o(float f) {
    unsigned u = __float_as_uint(f);
    return (u & 0x80000000u) ? ~u : (u | 0x80000000u);
}
__device__ __forceinline__ float o2f(unsigned u) {
    return (u & 0x80000000u) ? __uint_as_float(u ^ 0x80000000u)
                             : __uint_as_float(~u);
}

// ============================================================================
// Register-tiled f32 GEMM: C[m,o] = sum_i A[m,i]*B[i,o], K=O=128 fixed.
// 128x128 C-tile / block, 256 threads, 8x8 frags, BK=16.
// gridDim.y picks B-matrix k (node_pre: linear[k]) and C slab offset.
// EPI: fused bias + ReLU + per-column sum/sumsq atomics (mlp+BN stats).
// ============================================================================
template<bool EPI>
__global__ __launch_bounds__(256)
void gemm_nk(const float* __restrict__ A, const float* __restrict__ B_,
             float* __restrict__ C_, int M,
             const float* __restrict__ bias, float* __restrict__ sbuf) {
    const int kb = blockIdx.y;
    const float* B = B_ + (size_t)kb * FEAT * FEAT;
    float* C = C_ + (size_t)kb * (size_t)M * FEAT;
    const int m0 = blockIdx.x * 128;
    const int tid = threadIdx.x;
    const int tm = tid >> 4;        // 0..15 (node-frag group)
    const int to = tid & 15;        // 0..15 (col-frag group)

    __shared__ float lds[16 * 132 + 16 * 128];   // As[16][132] | Bs[16][128]
    float (*As)[132] = (float (*)[132])lds;
    float (*Bs)[128] = (float (*)[128])(lds + 16 * 132);

    float acc[8][8];
    #pragma unroll
    for (int i = 0; i < 8; ++i)
        #pragma unroll
        for (int j = 0; j < 8; ++j) acc[i][j] = 0.f;

    const int ra = tid >> 2;            // 0..63
    const int ca = (tid & 3) * 4;       // 0,4,8,12
    const int rb = tid >> 4;            // 0..15
    const int cb = (tid & 15) * 8;      // 0..120

    for (int ks = 0; ks < FEAT; ks += 16) {
        #pragma unroll
        for (int half = 0; half < 2; ++half) {
            const int r = ra + half * 64;
            const int gm = m0 + r;
            float4 v = make_float4(0.f, 0.f, 0.f, 0.f);
            if (gm < M) v = *(const float4*)(A + (size_t)gm * FEAT + ks + ca);
            As[ca + 0][r] = v.x; As[ca + 1][r] = v.y;
            As[ca + 2][r] = v.z; As[ca + 3][r] = v.w;
        }
        *(float4*)&Bs[rb][cb]     = *(const float4*)(B + (size_t)(ks + rb) * FEAT + cb);
        *(float4*)&Bs[rb][cb + 4] = *(const float4*)(B + (size_t)(ks + rb) * FEAT + cb + 4);
        __syncthreads();
        #pragma unroll
        for (int kk = 0; kk < 16; ++kk) {
            float a[8], b[8];
            *(float4*)&a[0] = *(const float4*)&As[kk][tm * 8];
            *(float4*)&a[4] = *(const float4*)&As[kk][tm * 8 + 4];
            *(float4*)&b[0] = *(const float4*)&Bs[kk][to * 8];
            *(float4*)&b[4] = *(const float4*)&Bs[kk][to * 8 + 4];
            #pragma unroll
            for (int i = 0; i < 8; ++i)
                #pragma unroll
                for (int j = 0; j < 8; ++j)
                    acc[i][j] = fmaf(a[i], b[j], acc[i][j]);
        }
        __syncthreads();
    }

    if (EPI) {
        float barr[8];
        #pragma unroll
        for (int j = 0; j < 8; ++j) barr[j] = bias[to * 8 + j];
        float s[8], s2[8];
        #pragma unroll
        for (int j = 0; j < 8; ++j) { s[j] = 0.f; s2[j] = 0.f; }
        #pragma unroll
        for (int i = 0; i < 8; ++i) {
            const int gm = m0 + tm * 8 + i;
            if (gm < M) {
                #pragma unroll
                for (int j = 0; j < 8; ++j) {
                    const float v = fmaxf(acc[i][j] + barr[j], 0.f);
                    acc[i][j] = v;
                    s[j] += v;
                    s2[j] = fmaf(v, v, s2[j]);
                }
                *(float4*)(C + (size_t)gm * FEAT + to * 8)     = *(float4*)&acc[i][0];
                *(float4*)(C + (size_t)gm * FEAT + to * 8 + 4) = *(float4*)&acc[i][4];
            }
        }
        // block-level column reduction, then one atomic per column
        __syncthreads();   // done with As/Bs — reuse lds
        float (*red)[128]  = (float (*)[128])lds;
        float (*red2)[128] = (float (*)[128])(lds + 2048);
        #pragma unroll
        for (int j = 0; j < 8; ++j) {
            red[tm][to * 8 + j]  = s[j];
            red2[tm][to * 8 + j] = s2[j];
        }
        __syncthreads();
        if (tid < 128) {
            float ss = 0.f, qq = 0.f;
            #pragma unroll
            for (int r = 0; r < 16; ++r) { ss += red[r][tid]; qq += red2[r][tid]; }
            atomicAdd(sbuf + tid, ss);
            atomicAdd(sbuf + FEAT + tid, qq);
        }
    } else {
        #pragma unroll
        for (int i = 0; i < 8; ++i) {
            const int gm = m0 + tm * 8 + i;
            if (gm < M) {
                *(float4*)(C + (size_t)gm * FEAT + to * 8)     = *(float4*)&acc[i][0];
                *(float4*)(C + (size_t)gm * FEAT + to * 8 + 4) = *(float4*)&acc[i][4];
            }
        }
    }
}

// ---- g[n,j] = sum_o attW[j,o] * feat[n,o]  (one wave per node) ----
__global__ void g_kernel(const float* __restrict__ feat,
                         const float* __restrict__ attW,
                         float* __restrict__ g) {
    const int node = (blockIdx.x * blockDim.x + threadIdx.x) >> 6;
    const int lane = threadIdx.x & 63;
    if (node >= N_NODES) return;
    const float2 f = *(const float2*)(feat + (size_t)node * FEAT + lane * 2);
    #pragma unroll
    for (int j = 0; j < 3; ++j) {
        float p = f.x * attW[j * FEAT + lane * 2] + f.y * attW[j * FEAT + lane * 2 + 1];
        #pragma unroll
        for (int off = 32; off; off >>= 1) p += __shfl_xor(p, off);
        if (lane == 0) g[node * 3 + j] = p;
    }
}

// ---- Wt[i,o] = W[o,i] ----
__global__ void wt_kernel(const float* __restrict__ W, float* __restrict__ Wt) {
    const int i = blockIdx.x;     // 128
    const int o = threadIdx.x;    // 128
    Wt[i * FEAT + o] = W[o * FEAT + i];
}

// ---- per-edge attention logits + inverse distance; segment max into m_u ----
__global__ void edge_att(const float* __restrict__ coords,
                         const float* __restrict__ g,
                         const int* __restrict__ src,
                         const int* __restrict__ dst,
                         float* __restrict__ ebuf,
                         float* __restrict__ invd,
                         unsigned* __restrict__ m_u) {
    const int e = blockIdx.x * blockDim.x + threadIdx.x;
    if (e >= E_EDGES) return;
    const int s = src[e], d = dst[e];
    const float dx = coords[s * 3 + 0] - coords[d * 3 + 0];
    const float dy = coords[s * 3 + 1] - coords[d * 3 + 1];
    const float dz = coords[s * 3 + 2] - coords[d * 3 + 2];
    const float a = dx * g[s * 3 + 0] + dy * g[s * 3 + 1] + dz * g[s * 3 + 2];
    ebuf[e] = a;
    invd[e] = 1.f / (dx * dx + dy * dy + dz * dz + 1.f);
    atomicMax(m_u + d, f2o(a));
}

__global__ void edge_exp(const int* __restrict__ dst,
                         const unsigned* __restrict__ m_u,
                         float* __restrict__ ebuf,
                         float* __restrict__ denom) {
    const int e = blockIdx.x * blockDim.x + threadIdx.x;
    if (e >= E_EDGES) return;
    const int d = dst[e];
    const float ex = expf(ebuf[e] - o2f(m_u[d]));
    ebuf[e] = ex;
    atomicAdd(denom + d, ex);
}

__global__ void edge_w(const int* __restrict__ dst,
                       const float* __restrict__ denom,
                       const float* __restrict__ invd,
                       float* __restrict__ ebuf) {
    const int e = blockIdx.x * blockDim.x + threadIdx.x;
    if (e >= E_EDGES) return;
    const float d = denom[dst[e]];
    ebuf[e] = ebuf[e] / (d > 0.f ? d : 1.f) * invd[e];
}

// ---- h[dst,:] += w[e] * xk[order[e], src[e], :]  (float4 gather, f32 atomics)
__global__ void scatter(const float* __restrict__ ebuf,
                        const float* __restrict__ xk,
                        const int* __restrict__ src,
                        const int* __restrict__ dst,
                        const int* __restrict__ order,
                        float* __restrict__ h) {
    const int idx = blockIdx.x * blockDim.x + threadIdx.x;   // < E*32
    const int e = idx >> 5;
    const int o4 = (idx & 31) * 4;
    const float w = ebuf[e];
    const float4 v = *(const float4*)(xk + ((size_t)order[e] * N_NODES + src[e]) * FEAT + o4);
    float* hp = h + (size_t)dst[e] * FEAT + o4;
    atomicAdd(hp + 0, w * v.x);
    atomicAdd(hp + 1, w * v.y);
    atomicAdd(hp + 2, w * v.z);
    atomicAdd(hp + 3, w * v.w);
}

// ---- mean/var -> scale/shift ----
__global__ void finalize(const float* __restrict__ sbuf,
                         const float* __restrict__ gamma,
                         const float* __restrict__ beta,
                         float* __restrict__ ss) {
    const int o = threadIdx.x;
    const float mean = sbuf[o] / (float)N_NODES;
    const float var  = sbuf[FEAT + o] / (float)N_NODES - mean * mean;
    const float sc   = gamma[o] * rsqrtf(var + BN_EPS);
    ss[o] = sc;
    ss[FEAT + o] = beta[o] - mean * sc;
}

// ---- out = out*scale + shift (in place, float4) ----
__global__ void normalize(float* __restrict__ y,
                          const float* __restrict__ ss) {
    const int idx = blockIdx.x * blockDim.x + threadIdx.x;   // N*32 threads
    const int o4 = (idx & 31) * 4;
    float4 v = *(float4*)(y + (size_t)idx * 4);
    const float4 sc = *(const float4*)(ss + o4);
    const float4 sh = *(const float4*)(ss + FEAT + o4);
    v.x = fmaf(v.x, sc.x, sh.x);
    v.y = fmaf(v.y, sc.y, sh.y);
    v.z = fmaf(v.z, sc.z, sh.z);
    v.w = fmaf(v.w, sc.w, sh.w);
    *(float4*)(y + (size_t)idx * 4) = v;
}

extern "C" void kernel_launch(void* const* d_in, const int* in_sizes, int n_in,
                              void* d_out, int out_size, void* d_ws, size_t ws_size,
                              hipStream_t stream) {
    const float* feature = (const float*)d_in[0];
    const float* coords  = (const float*)d_in[1];
    const int*   src     = (const int*)d_in[2];
    const int*   dst     = (const int*)d_in[3];
    const int*   order   = (const int*)d_in[4];
    const float* linear  = (const float*)d_in[5];
    const float* attW    = (const float*)d_in[6];
    const float* mlp_w   = (const float*)d_in[7];
    const float* mlp_b   = (const float*)d_in[8];
    const float* gamma   = (const float*)d_in[9];
    const float* beta    = (const float*)d_in[10];
    float* out = (float*)d_out;

    char* p = (char*)d_ws;
    float*    xk    = (float*)p;    p += (size_t)KORD * N_NODES * FEAT * 4;  // 76.8 MB
    float*    ebuf  = (float*)p;    p += (size_t)E_EDGES * 4;
    float*    invd  = (float*)p;    p += (size_t)E_EDGES * 4;
    unsigned* m_u   = (unsigned*)p; p += (size_t)N_NODES * 4;
    float*    denom = (float*)p;    p += (size_t)N_NODES * 4;
    float*    h     = (float*)p;    p += (size_t)N_NODES * FEAT * 4;         // 25.6 MB
    float*    g     = (float*)p;    p += (size_t)N_NODES * 3 * 4;
    float*    sbuf  = (float*)p;    p += 256 * 4;
    float*    ss    = (float*)p;    p += 256 * 4;
    float*    Wt    = (float*)p;    p += (size_t)FEAT * FEAT * 4;            // 64 KB

    hipMemsetAsync(m_u,   0, (size_t)N_NODES * 4, stream);
    hipMemsetAsync(denom, 0, (size_t)N_NODES * 4, stream);
    hipMemsetAsync(h,     0, (size_t)N_NODES * FEAT * 4, stream);
    hipMemsetAsync(sbuf,  0, 256 * 4, stream);

    wt_kernel<<<FEAT, FEAT, 0, stream>>>(mlp_w, Wt);
    g_kernel<<<(N_NODES + 3) / 4, 256, 0, stream>>>(feature, attW, g);

    const int MB = (N_NODES + 127) / 128;   // 391
    gemm_nk<false><<<dim3(MB, KORD), 256, 0, stream>>>(feature, linear, xk,
                                                       N_NODES, nullptr, nullptr);

    const int EB = (E_EDGES + 255) / 256;
    edge_att<<<EB, 256, 0, stream>>>(coords, g, src, dst, ebuf, invd, m_u);
    edge_exp<<<EB, 256, 0, stream>>>(dst, m_u, ebuf, denom);
    edge_w  <<<EB, 256, 0, stream>>>(dst, denom, invd, ebuf);

    scatter<<<(E_EDGES * 32) / 256, 256, 0, stream>>>(ebuf, xk, src, dst, order, h);

    gemm_nk<true><<<dim3(MB, 1), 256, 0, stream>>>(h, Wt, out, N_NODES, mlp_b, sbuf);
    finalize<<<1, FEAT, 0, stream>>>(sbuf, gamma, beta, ss);
    normalize<<<(N_NODES * 32) / 256, 256, 0, stream>>>(out, ss);
}

// Round 3
// 495.042 us; speedup vs baseline: 3.1628x; 3.1628x over previous
//
#include <hip/hip_runtime.h>

#define N_NODES 50000
#define E_EDGES 800000
#define FEAT    128
#define KORD    3
#define BN_EPS  1e-5f

// ============================================================================
// Register-tiled f32 GEMM: C[m,o] = sum_i A[m,i]*B[i,o], K=O=128 fixed.
// 128x128 C-tile / block, 256 threads, 8x8 frags, BK=16.
// gridDim.y picks B-matrix k (node_pre: linear[k]) and C slab offset.
// EPI: fused bias + ReLU + per-column sum/sumsq atomics (mlp+BN stats).
// ============================================================================
template<bool EPI>
__global__ __launch_bounds__(256)
void gemm_nk(const float* __restrict__ A, const float* __restrict__ B_,
             float* __restrict__ C_, int M,
             const float* __restrict__ bias, float* __restrict__ sbuf) {
    const int kb = blockIdx.y;
    const float* B = B_ + (size_t)kb * FEAT * FEAT;
    float* C = C_ + (size_t)kb * (size_t)M * FEAT;
    const int m0 = blockIdx.x * 128;
    const int tid = threadIdx.x;
    const int tm = tid >> 4;
    const int to = tid & 15;

    __shared__ float lds[16 * 132 + 16 * 128];
    float (*As)[132] = (float (*)[132])lds;
    float (*Bs)[128] = (float (*)[128])(lds + 16 * 132);

    float acc[8][8];
    #pragma unroll
    for (int i = 0; i < 8; ++i)
        #pragma unroll
        for (int j = 0; j < 8; ++j) acc[i][j] = 0.f;

    const int ra = tid >> 2;
    const int ca = (tid & 3) * 4;
    const int rb = tid >> 4;
    const int cb = (tid & 15) * 8;

    for (int ks = 0; ks < FEAT; ks += 16) {
        #pragma unroll
        for (int half = 0; half < 2; ++half) {
            const int r = ra + half * 64;
            const int gm = m0 + r;
            float4 v = make_float4(0.f, 0.f, 0.f, 0.f);
            if (gm < M) v = *(const float4*)(A + (size_t)gm * FEAT + ks + ca);
            As[ca + 0][r] = v.x; As[ca + 1][r] = v.y;
            As[ca + 2][r] = v.z; As[ca + 3][r] = v.w;
        }
        *(float4*)&Bs[rb][cb]     = *(const float4*)(B + (size_t)(ks + rb) * FEAT + cb);
        *(float4*)&Bs[rb][cb + 4] = *(const float4*)(B + (size_t)(ks + rb) * FEAT + cb + 4);
        __syncthreads();
        #pragma unroll
        for (int kk = 0; kk < 16; ++kk) {
            float a[8], b[8];
            *(float4*)&a[0] = *(const float4*)&As[kk][tm * 8];
            *(float4*)&a[4] = *(const float4*)&As[kk][tm * 8 + 4];
            *(float4*)&b[0] = *(const float4*)&Bs[kk][to * 8];
            *(float4*)&b[4] = *(const float4*)&Bs[kk][to * 8 + 4];
            #pragma unroll
            for (int i = 0; i < 8; ++i)
                #pragma unroll
                for (int j = 0; j < 8; ++j)
                    acc[i][j] = fmaf(a[i], b[j], acc[i][j]);
        }
        __syncthreads();
    }

    if (EPI) {
        float barr[8];
        #pragma unroll
        for (int j = 0; j < 8; ++j) barr[j] = bias[to * 8 + j];
        float s[8], s2[8];
        #pragma unroll
        for (int j = 0; j < 8; ++j) { s[j] = 0.f; s2[j] = 0.f; }
        #pragma unroll
        for (int i = 0; i < 8; ++i) {
            const int gm = m0 + tm * 8 + i;
            if (gm < M) {
                #pragma unroll
                for (int j = 0; j < 8; ++j) {
                    const float v = fmaxf(acc[i][j] + barr[j], 0.f);
                    acc[i][j] = v;
                    s[j] += v;
                    s2[j] = fmaf(v, v, s2[j]);
                }
                *(float4*)(C + (size_t)gm * FEAT + to * 8)     = *(float4*)&acc[i][0];
                *(float4*)(C + (size_t)gm * FEAT + to * 8 + 4) = *(float4*)&acc[i][4];
            }
        }
        __syncthreads();
        float (*red)[128]  = (float (*)[128])lds;
        float (*red2)[128] = (float (*)[128])(lds + 2048);
        #pragma unroll
        for (int j = 0; j < 8; ++j) {
            red[tm][to * 8 + j]  = s[j];
            red2[tm][to * 8 + j] = s2[j];
        }
        __syncthreads();
        if (tid < 128) {
            float ss = 0.f, qq = 0.f;
            #pragma unroll
            for (int r = 0; r < 16; ++r) { ss += red[r][tid]; qq += red2[r][tid]; }
            atomicAdd(sbuf + tid, ss);
            atomicAdd(sbuf + FEAT + tid, qq);
        }
    } else {
        #pragma unroll
        for (int i = 0; i < 8; ++i) {
            const int gm = m0 + tm * 8 + i;
            if (gm < M) {
                *(float4*)(C + (size_t)gm * FEAT + to * 8)     = *(float4*)&acc[i][0];
                *(float4*)(C + (size_t)gm * FEAT + to * 8 + 4) = *(float4*)&acc[i][4];
            }
        }
    }
}

// ---- g[n,j] = sum_o attW[j,o] * feat[n,o]  (one wave per node) ----
__global__ void g_kernel(const float* __restrict__ feat,
                         const float* __restrict__ attW,
                         float* __restrict__ g) {
    const int node = (blockIdx.x * blockDim.x + threadIdx.x) >> 6;
    const int lane = threadIdx.x & 63;
    if (node >= N_NODES) return;
    const float2 f = *(const float2*)(feat + (size_t)node * FEAT + lane * 2);
    #pragma unroll
    for (int j = 0; j < 3; ++j) {
        float p = f.x * attW[j * FEAT + lane * 2] + f.y * attW[j * FEAT + lane * 2 + 1];
        #pragma unroll
        for (int off = 32; off; off >>= 1) p += __shfl_xor(p, off);
        if (lane == 0) g[node * 3 + j] = p;
    }
}

// ---- Wt[i,o] = W[o,i] ----
__global__ void wt_kernel(const float* __restrict__ W, float* __restrict__ Wt) {
    Wt[blockIdx.x * FEAT + threadIdx.x] = W[threadIdx.x * FEAT + blockIdx.x];
}

// ---- per-edge attention logits + inverse distance (no atomics) ----
__global__ void edge_att(const float* __restrict__ coords,
                         const float* __restrict__ g,
                         const int* __restrict__ src,
                         const int* __restrict__ dst,
                         float* __restrict__ ebuf,
                         float* __restrict__ invd) {
    const int e = blockIdx.x * blockDim.x + threadIdx.x;
    if (e >= E_EDGES) return;
    const int s = src[e], d = dst[e];
    const float dx = coords[s * 3 + 0] - coords[d * 3 + 0];
    const float dy = coords[s * 3 + 1] - coords[d * 3 + 1];
    const float dz = coords[s * 3 + 2] - coords[d * 3 + 2];
    ebuf[e] = dx * g[s * 3 + 0] + dy * g[s * 3 + 1] + dz * g[s * 3 + 2];
    invd[e] = 1.f / (dx * dx + dy * dy + dz * dz + 1.f);
}

// ============ CSR build: histogram -> scan -> fill ============
__global__ void hist_kernel(const int* __restrict__ dst, int* __restrict__ cnt) {
    const int e = blockIdx.x * blockDim.x + threadIdx.x;
    if (e < E_EDGES) atomicAdd(cnt + dst[e], 1);
}

__global__ __launch_bounds__(1024) void scan_kernel(const int* __restrict__ cnt,
                                                    int* __restrict__ rowptr) {
    __shared__ int part[1024];
    const int t = threadIdx.x;
    const int chunk = (N_NODES + 1023) / 1024;
    const int beg = t * chunk;
    const int end = min(beg + chunk, N_NODES);
    int s = 0;
    for (int i = beg; i < end; ++i) s += cnt[i];
    part[t] = s;
    __syncthreads();
    for (int off = 1; off < 1024; off <<= 1) {
        const int v = (t >= off) ? part[t - off] : 0;
        __syncthreads();
        part[t] += v;
        __syncthreads();
    }
    int run = t ? part[t - 1] : 0;
    for (int i = beg; i < end; ++i) { rowptr[i] = run; run += cnt[i]; }
    if (t == 1023) rowptr[N_NODES] = run;
}

__global__ void fill_csr(const int* __restrict__ dst,
                         const int* __restrict__ rowptr,
                         int* __restrict__ cursor,
                         int* __restrict__ eid) {
    const int e = blockIdx.x * blockDim.x + threadIdx.x;
    if (e >= E_EDGES) return;
    const int d = dst[e];
    eid[rowptr[d] + atomicAdd(cursor + d, 1)] = e;
}

// ---- per-node segment softmax (one wave/node, in-place ebuf: att -> w) ----
__global__ void segsm(float* __restrict__ ebuf,
                      const float* __restrict__ invd,
                      const int* __restrict__ eid,
                      const int* __restrict__ rowptr) {
    const int node = (blockIdx.x * blockDim.x + threadIdx.x) >> 6;
    const int lane = threadIdx.x & 63;
    if (node >= N_NODES) return;
    const int beg = rowptr[node], end = rowptr[node + 1];
    float m = -3.402823e38f;
    for (int p = beg + lane; p < end; p += 64) m = fmaxf(m, ebuf[eid[p]]);
    #pragma unroll
    for (int off = 32; off; off >>= 1) m = fmaxf(m, __shfl_xor(m, off));
    float s = 0.f;
    for (int p = beg + lane; p < end; p += 64) s += expf(ebuf[eid[p]] - m);
    #pragma unroll
    for (int off = 32; off; off >>= 1) s += __shfl_xor(s, off);
    const float inv_s = 1.f / (s > 0.f ? s : 1.f);
    for (int p = beg + lane; p < end; p += 64) {
        const int e = eid[p];
        ebuf[e] = expf(ebuf[e] - m) * inv_s * invd[e];
    }
}

// ---- gather-aggregate: h[n,:] = sum_{e in CSR[n]} w[e]*xk[order[e],src[e],:]
__global__ void agg(const float* __restrict__ w,
                    const float* __restrict__ xk,
                    const int* __restrict__ eid,
                    const int* __restrict__ rowptr,
                    const int* __restrict__ src,
                    const int* __restrict__ order,
                    float* __restrict__ h) {
    const int node = (blockIdx.x * blockDim.x + threadIdx.x) >> 6;
    const int lane = threadIdx.x & 63;
    if (node >= N_NODES) return;
    const int beg = rowptr[node], end = rowptr[node + 1];
    float ax = 0.f, ay = 0.f;
    for (int p = beg; p < end; ++p) {
        const int e = eid[p];
        const float we = w[e];
        const float2 v = *(const float2*)(xk +
            ((size_t)order[e] * N_NODES + src[e]) * FEAT + lane * 2);
        ax = fmaf(we, v.x, ax);
        ay = fmaf(we, v.y, ay);
    }
    *(float2*)(h + (size_t)node * FEAT + lane * 2) = make_float2(ax, ay);
}

// ---- mean/var -> scale/shift ----
__global__ void finalize(const float* __restrict__ sbuf,
                         const float* __restrict__ gamma,
                         const float* __restrict__ beta,
                         float* __restrict__ ss) {
    const int o = threadIdx.x;
    const float mean = sbuf[o] / (float)N_NODES;
    const float var  = sbuf[FEAT + o] / (float)N_NODES - mean * mean;
    const float sc   = gamma[o] * rsqrtf(var + BN_EPS);
    ss[o] = sc;
    ss[FEAT + o] = beta[o] - mean * sc;
}

// ---- out = out*scale + shift (in place, float4) ----
__global__ void normalize(float* __restrict__ y,
                          const float* __restrict__ ss) {
    const int idx = blockIdx.x * blockDim.x + threadIdx.x;
    const int o4 = (idx & 31) * 4;
    float4 v = *(float4*)(y + (size_t)idx * 4);
    const float4 sc = *(const float4*)(ss + o4);
    const float4 sh = *(const float4*)(ss + FEAT + o4);
    v.x = fmaf(v.x, sc.x, sh.x);
    v.y = fmaf(v.y, sc.y, sh.y);
    v.z = fmaf(v.z, sc.z, sh.z);
    v.w = fmaf(v.w, sc.w, sh.w);
    *(float4*)(y + (size_t)idx * 4) = v;
}

extern "C" void kernel_launch(void* const* d_in, const int* in_sizes, int n_in,
                              void* d_out, int out_size, void* d_ws, size_t ws_size,
                              hipStream_t stream) {
    const float* feature = (const float*)d_in[0];
    const float* coords  = (const float*)d_in[1];
    const int*   src     = (const int*)d_in[2];
    const int*   dst     = (const int*)d_in[3];
    const int*   order   = (const int*)d_in[4];
    const float* linear  = (const float*)d_in[5];
    const float* attW    = (const float*)d_in[6];
    const float* mlp_w   = (const float*)d_in[7];
    const float* mlp_b   = (const float*)d_in[8];
    const float* gamma   = (const float*)d_in[9];
    const float* beta    = (const float*)d_in[10];
    float* out = (float*)d_out;

    char* p = (char*)d_ws;
    float* xk     = (float*)p; p += (size_t)KORD * N_NODES * FEAT * 4;  // 76.8 MB
    float* ebuf   = (float*)p; p += (size_t)E_EDGES * 4;                //  3.2 MB
    float* invd   = (float*)p; p += (size_t)E_EDGES * 4;                //  3.2 MB
    float* h      = (float*)p; p += (size_t)N_NODES * FEAT * 4;         // 25.6 MB
    float* g      = (float*)p; p += (size_t)N_NODES * 3 * 4;
    float* sbuf   = (float*)p; p += 256 * 4;
    float* ss     = (float*)p; p += 256 * 4;
    float* Wt     = (float*)p; p += (size_t)FEAT * FEAT * 4;
    int*   cnt    = (int*)p;   p += (size_t)N_NODES * 4;
    int*   cursor = (int*)p;   p += (size_t)N_NODES * 4;
    int*   rowptr = (int*)p;   p += (size_t)(N_NODES + 1) * 4;
    int*   eid    = (int*)p;   p += (size_t)E_EDGES * 4;                //  3.2 MB

    hipMemsetAsync(cnt,    0, (size_t)N_NODES * 4, stream);
    hipMemsetAsync(cursor, 0, (size_t)N_NODES * 4, stream);
    hipMemsetAsync(sbuf,   0, 256 * 4, stream);

    const int EB = (E_EDGES + 255) / 256;
    const int NWB = (N_NODES * 64 + 255) / 256;   // 1 wave per node, 256-thr blocks

    wt_kernel<<<FEAT, FEAT, 0, stream>>>(mlp_w, Wt);
    g_kernel<<<NWB, 256, 0, stream>>>(feature, attW, g);

    const int MB = (N_NODES + 127) / 128;
    gemm_nk<false><<<dim3(MB, KORD), 256, 0, stream>>>(feature, linear, xk,
                                                       N_NODES, nullptr, nullptr);

    hist_kernel<<<EB, 256, 0, stream>>>(dst, cnt);
    scan_kernel<<<1, 1024, 0, stream>>>(cnt, rowptr);
    fill_csr<<<EB, 256, 0, stream>>>(dst, rowptr, cursor, eid);

    edge_att<<<EB, 256, 0, stream>>>(coords, g, src, dst, ebuf, invd);
    segsm<<<NWB, 256, 0, stream>>>(ebuf, invd, eid, rowptr);
    agg<<<NWB, 256, 0, stream>>>(ebuf, xk, eid, rowptr, src, order, h);

    gemm_nk<true><<<dim3(MB, 1), 256, 0, stream>>>(h, Wt, out, N_NODES, mlp_b, sbuf);
    finalize<<<1, FEAT, 0, stream>>>(sbuf, gamma, beta, ss);
    normalize<<<(N_NODES * 32) / 256, 256, 0, stream>>>(out, ss);
}

// Round 5
// 321.498 us; speedup vs baseline: 4.8700x; 1.5398x over previous
//
#include <hip/hip_runtime.h>

#define N_NODES 50000
#define E_EDGES 800000
#define FEAT    128
#define KORD    3
#define BN_EPS  1e-5f

typedef __attribute__((ext_vector_type(8))) short bf16x8;
typedef __attribute__((ext_vector_type(4))) float f32x4;

__device__ __forceinline__ unsigned short f2bf(float f) {   // RNE f32->bf16
    unsigned u = __float_as_uint(f);
    u += 0x7FFFu + ((u >> 16) & 1u);
    return (unsigned short)(u >> 16);
}
__device__ __forceinline__ float bflo(unsigned u) { return __uint_as_float(u << 16); }
__device__ __forceinline__ float bfhi(unsigned u) { return __uint_as_float(u & 0xFFFF0000u); }

// ---- mlp_w [o][i] f32 -> bf16 (row-major == B^T layout the GEMM wants) ----
__global__ void wcast(const float* __restrict__ W, unsigned short* __restrict__ Wb) {
    const int i = blockIdx.x * 256 + threadIdx.x;   // 16384
    Wb[i] = f2bf(W[i]);
}

// ---- linT[k][o][i] = bf16(linear[k][i][o]) ----
__global__ void lincast(const float* __restrict__ L, unsigned short* __restrict__ Lt) {
    const int k = blockIdx.x >> 7;
    const int o = blockIdx.x & 127;
    const int i = threadIdx.x;
    Lt[((size_t)k * FEAT + o) * FEAT + i] = f2bf(L[((size_t)k * FEAT + i) * FEAT + o]);
}

// ---- per node: feature->bf16, and pack {coords, g=attW@f} into 2 float4 ----
__global__ void g_cast(const float* __restrict__ feat,
                       const float* __restrict__ coords,
                       const float* __restrict__ attW,
                       unsigned short* __restrict__ fb,
                       float4* __restrict__ pk) {
    const int node = (blockIdx.x * blockDim.x + threadIdx.x) >> 6;
    const int lane = threadIdx.x & 63;
    if (node >= N_NODES) return;
    const float2 f = *(const float2*)(feat + (size_t)node * FEAT + lane * 2);
    *(unsigned*)(fb + (size_t)node * FEAT + lane * 2) =
        (unsigned)f2bf(f.x) | ((unsigned)f2bf(f.y) << 16);
    float gg[3];
    #pragma unroll
    for (int j = 0; j < 3; ++j) {
        float p = f.x * attW[j * FEAT + lane * 2] + f.y * attW[j * FEAT + lane * 2 + 1];
        #pragma unroll
        for (int off = 32; off; off >>= 1) p += __shfl_xor(p, off);
        gg[j] = p;
    }
    if (lane == 0) {
        const float c0 = coords[node * 3 + 0], c1 = coords[node * 3 + 1], c2 = coords[node * 3 + 2];
        pk[2 * node]     = make_float4(c0, c1, c2, gg[0]);
        pk[2 * node + 1] = make_float4(gg[1], gg[2], 0.f, 0.f);
    }
}

// ============================================================================
// bf16 MFMA GEMM, K=N=128 fixed: C[m,o] = sum_i A[m,i]*B^T[o,i]
// block = 256 thr (4 waves), M-tile 128 (32 rows/wave), full K in LDS.
// LDS tiles XOR-swizzled (byte ^= (row&7)<<4) on write AND read (T2).
// !EPI: C -> bf16 (slab kb) via LDS re-stage (coalesced 16B stores).
//  EPI: C -> f32 + bias + ReLU + BN column stats (LDS reduce + atomics).
// ============================================================================
template<bool EPI>
__global__ __launch_bounds__(256)
void gemm_mfma(const unsigned short* __restrict__ A,
               const unsigned short* __restrict__ B_,
               void* __restrict__ C_, int M,
               const float* __restrict__ bias, float* __restrict__ sbuf) {
    __shared__ char smem[65536];
    const int kb = blockIdx.y;
    const unsigned short* B = B_ + (size_t)kb * FEAT * FEAT;
    const size_t c_off = (size_t)kb * (size_t)M * FEAT;   // <-- round-4 bug: was missing
    const int m0 = blockIdx.x * 128;
    const int tid = threadIdx.x;

    // stage A-tile (32KB) + B-tile (32KB), swizzled
    for (int p = tid; p < 2048; p += 256) {
        const int row = p >> 4, chunk = p & 15;
        const int off = ((row << 8) + (chunk << 4)) ^ ((row & 7) << 4);
        float4 va = make_float4(0.f, 0.f, 0.f, 0.f);
        if (m0 + row < M) va = *(const float4*)(A + (size_t)(m0 + row) * FEAT + chunk * 8);
        *(float4*)(smem + off) = va;
        *(float4*)(smem + 32768 + off) = *(const float4*)(B + (size_t)row * FEAT + chunk * 8);
    }
    __syncthreads();

    const int wave = tid >> 6, lane = tid & 63;
    const int wm0 = wave * 32;
    const int lrow = lane & 15;
    const int kslot = (lane >> 4) << 4;          // byte offset of lane's 8 bf16 in k
    const int swz = (lrow & 7) << 4;

    f32x4 acc[2][8];
    #pragma unroll
    for (int a = 0; a < 2; ++a)
        #pragma unroll
        for (int b = 0; b < 8; ++b) acc[a][b] = (f32x4){0.f, 0.f, 0.f, 0.f};

    bf16x8 afr[2][4];
    #pragma unroll
    for (int mf = 0; mf < 2; ++mf)
        #pragma unroll
        for (int ks = 0; ks < 4; ++ks) {
            const int row = wm0 + mf * 16 + lrow;
            afr[mf][ks] = *(const bf16x8*)(smem + (((row << 8) + (ks << 6) + kslot) ^ swz));
        }
    #pragma unroll
    for (int nf = 0; nf < 8; ++nf) {
        #pragma unroll
        for (int ks = 0; ks < 4; ++ks) {
            const int row = nf * 16 + lrow;
            bf16x8 bfr = *(const bf16x8*)(smem + 32768 + (((row << 8) + (ks << 6) + kslot) ^ swz));
            acc[0][nf] = __builtin_amdgcn_mfma_f32_16x16x32_bf16(afr[0][ks], bfr, acc[0][nf], 0, 0, 0);
            acc[1][nf] = __builtin_amdgcn_mfma_f32_16x16x32_bf16(afr[1][ks], bfr, acc[1][nf], 0, 0, 0);
        }
    }

    if (!EPI) {
        __syncthreads();
        float* Cs = (float*)smem;                 // [128][128] f32 re-stage
        #pragma unroll
        for (int mf = 0; mf < 2; ++mf)
            #pragma unroll
            for (int nf = 0; nf < 8; ++nf)
                #pragma unroll
                for (int rg = 0; rg < 4; ++rg)
                    Cs[(wm0 + mf * 16 + (lane >> 4) * 4 + rg) * 128 + nf * 16 + lrow] = acc[mf][nf][rg];
        __syncthreads();
        unsigned short* Cb = (unsigned short*)C_ + c_off;
        const int r = tid >> 1, half = tid & 1;
        if (m0 + r < M) {
            const float* srcp = Cs + r * 128 + half * 64;
            #pragma unroll
            for (int j = 0; j < 64; j += 8) {
                unsigned short tmp[8];
                #pragma unroll
                for (int q = 0; q < 8; ++q) tmp[q] = f2bf(srcp[j + q]);
                *(uint4*)(Cb + (size_t)(m0 + r) * FEAT + half * 64 + j) = *(uint4*)tmp;
            }
        }
    } else {
        float* C = (float*)C_ + c_off;
        float s[8], s2[8], bv[8];
        #pragma unroll
        for (int nf = 0; nf < 8; ++nf) { s[nf] = 0.f; s2[nf] = 0.f; bv[nf] = bias[nf * 16 + lrow]; }
        #pragma unroll
        for (int mf = 0; mf < 2; ++mf)
            #pragma unroll
            for (int nf = 0; nf < 8; ++nf)
                #pragma unroll
                for (int rg = 0; rg < 4; ++rg) {
                    const int row = m0 + wm0 + mf * 16 + (lane >> 4) * 4 + rg;
                    if (row < M) {
                        const float v = fmaxf(acc[mf][nf][rg] + bv[nf], 0.f);
                        C[(size_t)row * FEAT + nf * 16 + lrow] = v;
                        s[nf] += v;
                        s2[nf] = fmaf(v, v, s2[nf]);
                    }
                }
        #pragma unroll
        for (int nf = 0; nf < 8; ++nf) {
            s[nf]  += __shfl_xor(s[nf], 16);  s[nf]  += __shfl_xor(s[nf], 32);
            s2[nf] += __shfl_xor(s2[nf], 16); s2[nf] += __shfl_xor(s2[nf], 32);
        }
        __syncthreads();
        float* red = (float*)smem;                // [4][256]
        if (lane < 16) {
            #pragma unroll
            for (int nf = 0; nf < 8; ++nf) {
                red[wave * 256 + nf * 16 + lane]       = s[nf];
                red[wave * 256 + 128 + nf * 16 + lane] = s2[nf];
            }
        }
        __syncthreads();
        if (tid < 128) {
            const float ss = red[tid] + red[256 + tid] + red[512 + tid] + red[768 + tid];
            const float qq = red[128 + tid] + red[384 + tid] + red[640 + tid] + red[896 + tid];
            atomicAdd(sbuf + tid, ss);
            atomicAdd(sbuf + FEAT + tid, qq);
        }
    }
}

// ============ CSR build ============
__global__ void hist_kernel(const int* __restrict__ dst, int* __restrict__ cnt) {
    const int e = blockIdx.x * blockDim.x + threadIdx.x;
    if (e < E_EDGES) atomicAdd(cnt + dst[e], 1);
}

__global__ __launch_bounds__(1024) void scan_kernel(const int* __restrict__ cnt,
                                                    int* __restrict__ rowptr) {
    __shared__ int part[1024];
    const int t = threadIdx.x;
    const int chunk = (N_NODES + 1023) / 1024;
    const int beg = t * chunk;
    const int end = min(beg + chunk, N_NODES);
    int s = 0;
    for (int i = beg; i < end; ++i) s += cnt[i];
    part[t] = s;
    __syncthreads();
    for (int off = 1; off < 1024; off <<= 1) {
        const int v = (t >= off) ? part[t - off] : 0;
        __syncthreads();
        part[t] += v;
        __syncthreads();
    }
    int run = t ? part[t - 1] : 0;
    for (int i = beg; i < end; ++i) { rowptr[i] = run; run += cnt[i]; }
    if (t == 1023) rowptr[N_NODES] = run;
}

// fill CSR slots with packed (order<<16)|src and dst (row id)
__global__ void fill_csr(const int* __restrict__ src, const int* __restrict__ dst,
                         const int* __restrict__ order, const int* __restrict__ rowptr,
                         int* __restrict__ cursor,
                         int* __restrict__ sord_p, int* __restrict__ dst_p) {
    const int e = blockIdx.x * blockDim.x + threadIdx.x;
    if (e >= E_EDGES) return;
    const int d = dst[e];
    const int pos = rowptr[d] + atomicAdd(cursor + d, 1);
    sord_p[pos] = (order[e] << 16) | src[e];
    dst_p[pos] = d;
}

// ---- per-edge (CSR order): attention logit + inv-dist, all streams ----
__global__ void edge_att(const float4* __restrict__ pk,
                         const int* __restrict__ sord_p,
                         const int* __restrict__ dst_p,
                         float* __restrict__ att_p,
                         float* __restrict__ invd_p) {
    const int e = blockIdx.x * blockDim.x + threadIdx.x;
    if (e >= E_EDGES) return;
    const int s = sord_p[e] & 0xFFFF;
    const int d = dst_p[e];
    const float4 a0 = pk[2 * s], a1 = pk[2 * s + 1], b0 = pk[2 * d];
    const float dx = a0.x - b0.x, dy = a0.y - b0.y, dz = a0.z - b0.z;
    att_p[e]  = dx * a0.w + dy * a1.x + dz * a1.y;
    invd_p[e] = 1.f / (dx * dx + dy * dy + dz * dz + 1.f);
}

// ---- per-node segment softmax over contiguous CSR range ----
__global__ void segsm(const float* __restrict__ att_p,
                      const float* __restrict__ invd_p,
                      const int* __restrict__ rowptr,
                      float* __restrict__ w_p) {
    const int node = (blockIdx.x * blockDim.x + threadIdx.x) >> 6;
    const int lane = threadIdx.x & 63;
    if (node >= N_NODES) return;
    const int beg = rowptr[node], end = rowptr[node + 1];
    float m = -3.402823e38f;
    for (int p = beg + lane; p < end; p += 64) m = fmaxf(m, att_p[p]);
    #pragma unroll
    for (int off = 32; off; off >>= 1) m = fmaxf(m, __shfl_xor(m, off));
    float s = 0.f;
    for (int p = beg + lane; p < end; p += 64) {
        const float ex = __expf(att_p[p] - m);
        w_p[p] = ex;
        s += ex;
    }
    #pragma unroll
    for (int off = 32; off; off >>= 1) s += __shfl_xor(s, off);
    const float inv_s = 1.f / (s > 0.f ? s : 1.f);
    for (int p = beg + lane; p < end; p += 64) w_p[p] = w_p[p] * inv_s * invd_p[p];
}

// ---- gather-aggregate (bf16 xk, 4-deep pipelined), writes bf16 h ----
__global__ void agg(const float* __restrict__ w_p,
                    const int* __restrict__ sord_p,
                    const int* __restrict__ rowptr,
                    const unsigned short* __restrict__ xk,
                    unsigned short* __restrict__ hb) {
    const int node = (blockIdx.x * blockDim.x + threadIdx.x) >> 6;
    const int lane = threadIdx.x & 63;
    if (node >= N_NODES) return;
    const int beg = rowptr[node], end = rowptr[node + 1];
    float ax = 0.f, ay = 0.f;
    int p = beg;
    for (; p + 4 <= end; p += 4) {
        const int so0 = sord_p[p], so1 = sord_p[p + 1], so2 = sord_p[p + 2], so3 = sord_p[p + 3];
        const float w0 = w_p[p], w1 = w_p[p + 1], w2 = w_p[p + 2], w3 = w_p[p + 3];
        const unsigned v0 = *(const unsigned*)(xk + (((size_t)(so0 >> 16) * N_NODES + (so0 & 0xFFFF)) << 7) + lane * 2);
        const unsigned v1 = *(const unsigned*)(xk + (((size_t)(so1 >> 16) * N_NODES + (so1 & 0xFFFF)) << 7) + lane * 2);
        const unsigned v2 = *(const unsigned*)(xk + (((size_t)(so2 >> 16) * N_NODES + (so2 & 0xFFFF)) << 7) + lane * 2);
        const unsigned v3 = *(const unsigned*)(xk + (((size_t)(so3 >> 16) * N_NODES + (so3 & 0xFFFF)) << 7) + lane * 2);
        ax = fmaf(w0, bflo(v0), ax); ay = fmaf(w0, bfhi(v0), ay);
        ax = fmaf(w1, bflo(v1), ax); ay = fmaf(w1, bfhi(v1), ay);
        ax = fmaf(w2, bflo(v2), ax); ay = fmaf(w2, bfhi(v2), ay);
        ax = fmaf(w3, bflo(v3), ax); ay = fmaf(w3, bfhi(v3), ay);
    }
    for (; p < end; ++p) {
        const int so = sord_p[p];
        const float w = w_p[p];
        const unsigned v = *(const unsigned*)(xk + (((size_t)(so >> 16) * N_NODES + (so & 0xFFFF)) << 7) + lane * 2);
        ax = fmaf(w, bflo(v), ax); ay = fmaf(w, bfhi(v), ay);
    }
    *(unsigned*)(hb + ((size_t)node << 7) + lane * 2) =
        (unsigned)f2bf(ax) | ((unsigned)f2bf(ay) << 16);
}

// ---- mean/var -> scale/shift ----
__global__ void finalize(const float* __restrict__ sbuf,
                         const float* __restrict__ gamma,
                         const float* __restrict__ beta,
                         float* __restrict__ ss) {
    const int o = threadIdx.x;
    const float mean = sbuf[o] / (float)N_NODES;
    const float var  = sbuf[FEAT + o] / (float)N_NODES - mean * mean;
    const float sc   = gamma[o] * rsqrtf(var + BN_EPS);
    ss[o] = sc;
    ss[FEAT + o] = beta[o] - mean * sc;
}

// ---- out = out*scale + shift (in place, float4) ----
__global__ void normalize(float* __restrict__ y, const float* __restrict__ ss) {
    const int idx = blockIdx.x * blockDim.x + threadIdx.x;
    const int o4 = (idx & 31) * 4;
    float4 v = *(float4*)(y + (size_t)idx * 4);
    const float4 sc = *(const float4*)(ss + o4);
    const float4 sh = *(const float4*)(ss + FEAT + o4);
    v.x = fmaf(v.x, sc.x, sh.x);
    v.y = fmaf(v.y, sc.y, sh.y);
    v.z = fmaf(v.z, sc.z, sh.z);
    v.w = fmaf(v.w, sc.w, sh.w);
    *(float4*)(y + (size_t)idx * 4) = v;
}

extern "C" void kernel_launch(void* const* d_in, const int* in_sizes, int n_in,
                              void* d_out, int out_size, void* d_ws, size_t ws_size,
                              hipStream_t stream) {
    const float* feature = (const float*)d_in[0];
    const float* coords  = (const float*)d_in[1];
    const int*   src     = (const int*)d_in[2];
    const int*   dst     = (const int*)d_in[3];
    const int*   order   = (const int*)d_in[4];
    const float* linear  = (const float*)d_in[5];
    const float* attW    = (const float*)d_in[6];
    const float* mlp_w   = (const float*)d_in[7];
    const float* mlp_b   = (const float*)d_in[8];
    const float* gamma   = (const float*)d_in[9];
    const float* beta    = (const float*)d_in[10];
    float* out = (float*)d_out;

    char* p = (char*)d_ws;
    unsigned short* xk   = (unsigned short*)p; p += (size_t)KORD * N_NODES * FEAT * 2;  // 38.4 MB
    unsigned short* fb   = (unsigned short*)p; p += (size_t)N_NODES * FEAT * 2;         // 12.8 MB
    unsigned short* hb   = (unsigned short*)p; p += (size_t)N_NODES * FEAT * 2;         // 12.8 MB
    unsigned short* linT = (unsigned short*)p; p += (size_t)KORD * FEAT * FEAT * 2;     // 98 KB
    unsigned short* Wb   = (unsigned short*)p; p += (size_t)FEAT * FEAT * 2;            // 32 KB
    float4* pk           = (float4*)p;         p += (size_t)N_NODES * 32;               // 1.6 MB
    float* att_p         = (float*)p;          p += (size_t)E_EDGES * 4;
    float* invd_p        = (float*)p;          p += (size_t)E_EDGES * 4;
    float* w_p           = (float*)p;          p += (size_t)E_EDGES * 4;
    int*   sord_p        = (int*)p;            p += (size_t)E_EDGES * 4;
    int*   dst_p         = (int*)p;            p += (size_t)E_EDGES * 4;
    int*   rowptr        = (int*)p;            p += 200064;
    int*   cnt           = (int*)p;            p += 200064;   // cnt|cursor|sbuf contiguous
    int*   cursor        = (int*)p;            p += 200064;
    float* sbuf          = (float*)p;          p += 1024;
    float* ss            = (float*)p;          p += 1024;

    // one memset covers cnt + cursor + sbuf
    hipMemsetAsync(cnt, 0, 200064 * 2 + 1024, stream);

    const int EB  = (E_EDGES + 255) / 256;        // 3125
    const int NWB = (N_NODES * 64) / 256;         // 12500
    const int MB  = (N_NODES + 127) / 128;        // 391

    wcast  <<<64, 256, 0, stream>>>(mlp_w, Wb);
    lincast<<<KORD * FEAT, FEAT, 0, stream>>>(linear, linT);
    g_cast <<<NWB, 256, 0, stream>>>(feature, coords, attW, fb, pk);

    gemm_mfma<false><<<dim3(MB, KORD), 256, 0, stream>>>(fb, linT, xk, N_NODES, nullptr, nullptr);

    hist_kernel<<<EB, 256, 0, stream>>>(dst, cnt);
    scan_kernel<<<1, 1024, 0, stream>>>(cnt, rowptr);
    fill_csr<<<EB, 256, 0, stream>>>(src, dst, order, rowptr, cursor, sord_p, dst_p);

    edge_att<<<EB, 256, 0, stream>>>(pk, sord_p, dst_p, att_p, invd_p);
    segsm<<<NWB, 256, 0, stream>>>(att_p, invd_p, rowptr, w_p);
    agg<<<NWB, 256, 0, stream>>>(w_p, sord_p, rowptr, xk, hb);

    gemm_mfma<true><<<dim3(MB, 1), 256, 0, stream>>>(hb, Wb, out, N_NODES, mlp_b, sbuf);
    finalize<<<1, FEAT, 0, stream>>>(sbuf, gamma, beta, ss);
    normalize<<<(N_NODES * 32) / 256, 256, 0, stream>>>(out, ss);
}

// Round 6
// 235.393 us; speedup vs baseline: 6.6515x; 1.3658x over previous
//
#include <hip/hip_runtime.h>

#define N_NODES 50000
#define E_EDGES 800000
#define FEAT    128
#define KORD    3
#define BN_EPS  1e-5f
#define NB1     49          // ceil(50000/1024) scan blocks

typedef __attribute__((ext_vector_type(8))) short bf16x8;
typedef __attribute__((ext_vector_type(4))) float f32x4;

__device__ __forceinline__ unsigned short f2bf(float f) {   // RNE f32->bf16
    unsigned u = __float_as_uint(f);
    u += 0x7FFFu + ((u >> 16) & 1u);
    return (unsigned short)(u >> 16);
}
__device__ __forceinline__ float bflo(unsigned u) { return __uint_as_float(u << 16); }
__device__ __forceinline__ float bfhi(unsigned u) { return __uint_as_float(u & 0xFFFF0000u); }

// ---- mlp_w [o][i] f32 -> bf16 (row-major == B^T layout the GEMM wants) ----
__global__ void wcast(const float* __restrict__ W, unsigned short* __restrict__ Wb) {
    const int i = blockIdx.x * 256 + threadIdx.x;   // 16384
    Wb[i] = f2bf(W[i]);
}

// ---- linT[k][o][i] = bf16(linear[k][i][o]) ----
__global__ void lincast(const float* __restrict__ L, unsigned short* __restrict__ Lt) {
    const int k = blockIdx.x >> 7;
    const int o = blockIdx.x & 127;
    const int i = threadIdx.x;
    Lt[((size_t)k * FEAT + o) * FEAT + i] = f2bf(L[((size_t)k * FEAT + i) * FEAT + o]);
}

// ---- per node: feature->bf16, and pack {coords, g=attW@f} into 2 float4 ----
__global__ void g_cast(const float* __restrict__ feat,
                       const float* __restrict__ coords,
                       const float* __restrict__ attW,
                       unsigned short* __restrict__ fb,
                       float4* __restrict__ pk) {
    const int node = (blockIdx.x * blockDim.x + threadIdx.x) >> 6;
    const int lane = threadIdx.x & 63;
    if (node >= N_NODES) return;
    const float2 f = *(const float2*)(feat + (size_t)node * FEAT + lane * 2);
    *(unsigned*)(fb + (size_t)node * FEAT + lane * 2) =
        (unsigned)f2bf(f.x) | ((unsigned)f2bf(f.y) << 16);
    float gg[3];
    #pragma unroll
    for (int j = 0; j < 3; ++j) {
        float p = f.x * attW[j * FEAT + lane * 2] + f.y * attW[j * FEAT + lane * 2 + 1];
        #pragma unroll
        for (int off = 32; off; off >>= 1) p += __shfl_xor(p, off);
        gg[j] = p;
    }
    if (lane == 0) {
        const float c0 = coords[node * 3 + 0], c1 = coords[node * 3 + 1], c2 = coords[node * 3 + 2];
        pk[2 * node]     = make_float4(c0, c1, c2, gg[0]);
        pk[2 * node + 1] = make_float4(gg[1], gg[2], 0.f, 0.f);
    }
}

// ============================================================================
// bf16 MFMA GEMM, K=N=128 fixed: C[m,o] = sum_i A[m,i]*B^T[o,i]
// ============================================================================
template<bool EPI>
__global__ __launch_bounds__(256)
void gemm_mfma(const unsigned short* __restrict__ A,
               const unsigned short* __restrict__ B_,
               void* __restrict__ C_, int M,
               const float* __restrict__ bias, float* __restrict__ sbuf) {
    __shared__ char smem[65536];
    const int kb = blockIdx.y;
    const unsigned short* B = B_ + (size_t)kb * FEAT * FEAT;
    const size_t c_off = (size_t)kb * (size_t)M * FEAT;
    const int m0 = blockIdx.x * 128;
    const int tid = threadIdx.x;

    for (int p = tid; p < 2048; p += 256) {
        const int row = p >> 4, chunk = p & 15;
        const int off = ((row << 8) + (chunk << 4)) ^ ((row & 7) << 4);
        float4 va = make_float4(0.f, 0.f, 0.f, 0.f);
        if (m0 + row < M) va = *(const float4*)(A + (size_t)(m0 + row) * FEAT + chunk * 8);
        *(float4*)(smem + off) = va;
        *(float4*)(smem + 32768 + off) = *(const float4*)(B + (size_t)row * FEAT + chunk * 8);
    }
    __syncthreads();

    const int wave = tid >> 6, lane = tid & 63;
    const int wm0 = wave * 32;
    const int lrow = lane & 15;
    const int kslot = (lane >> 4) << 4;
    const int swz = (lrow & 7) << 4;

    f32x4 acc[2][8];
    #pragma unroll
    for (int a = 0; a < 2; ++a)
        #pragma unroll
        for (int b = 0; b < 8; ++b) acc[a][b] = (f32x4){0.f, 0.f, 0.f, 0.f};

    bf16x8 afr[2][4];
    #pragma unroll
    for (int mf = 0; mf < 2; ++mf)
        #pragma unroll
        for (int ks = 0; ks < 4; ++ks) {
            const int row = wm0 + mf * 16 + lrow;
            afr[mf][ks] = *(const bf16x8*)(smem + (((row << 8) + (ks << 6) + kslot) ^ swz));
        }
    #pragma unroll
    for (int nf = 0; nf < 8; ++nf) {
        #pragma unroll
        for (int ks = 0; ks < 4; ++ks) {
            const int row = nf * 16 + lrow;
            bf16x8 bfr = *(const bf16x8*)(smem + 32768 + (((row << 8) + (ks << 6) + kslot) ^ swz));
            acc[0][nf] = __builtin_amdgcn_mfma_f32_16x16x32_bf16(afr[0][ks], bfr, acc[0][nf], 0, 0, 0);
            acc[1][nf] = __builtin_amdgcn_mfma_f32_16x16x32_bf16(afr[1][ks], bfr, acc[1][nf], 0, 0, 0);
        }
    }

    if (!EPI) {
        __syncthreads();
        float* Cs = (float*)smem;
        #pragma unroll
        for (int mf = 0; mf < 2; ++mf)
            #pragma unroll
            for (int nf = 0; nf < 8; ++nf)
                #pragma unroll
                for (int rg = 0; rg < 4; ++rg)
                    Cs[(wm0 + mf * 16 + (lane >> 4) * 4 + rg) * 128 + nf * 16 + lrow] = acc[mf][nf][rg];
        __syncthreads();
        unsigned short* Cb = (unsigned short*)C_ + c_off;
        const int r = tid >> 1, half = tid & 1;
        if (m0 + r < M) {
            const float* srcp = Cs + r * 128 + half * 64;
            #pragma unroll
            for (int j = 0; j < 64; j += 8) {
                unsigned short tmp[8];
                #pragma unroll
                for (int q = 0; q < 8; ++q) tmp[q] = f2bf(srcp[j + q]);
                *(uint4*)(Cb + (size_t)(m0 + r) * FEAT + half * 64 + j) = *(uint4*)tmp;
            }
        }
    } else {
        float* C = (float*)C_ + c_off;
        float s[8], s2[8], bv[8];
        #pragma unroll
        for (int nf = 0; nf < 8; ++nf) { s[nf] = 0.f; s2[nf] = 0.f; bv[nf] = bias[nf * 16 + lrow]; }
        #pragma unroll
        for (int mf = 0; mf < 2; ++mf)
            #pragma unroll
            for (int nf = 0; nf < 8; ++nf)
                #pragma unroll
                for (int rg = 0; rg < 4; ++rg) {
                    const int row = m0 + wm0 + mf * 16 + (lane >> 4) * 4 + rg;
                    if (row < M) {
                        const float v = fmaxf(acc[mf][nf][rg] + bv[nf], 0.f);
                        C[(size_t)row * FEAT + nf * 16 + lrow] = v;
                        s[nf] += v;
                        s2[nf] = fmaf(v, v, s2[nf]);
                    }
                }
        #pragma unroll
        for (int nf = 0; nf < 8; ++nf) {
            s[nf]  += __shfl_xor(s[nf], 16);  s[nf]  += __shfl_xor(s[nf], 32);
            s2[nf] += __shfl_xor(s2[nf], 16); s2[nf] += __shfl_xor(s2[nf], 32);
        }
        __syncthreads();
        float* red = (float*)smem;
        if (lane < 16) {
            #pragma unroll
            for (int nf = 0; nf < 8; ++nf) {
                red[wave * 256 + nf * 16 + lane]       = s[nf];
                red[wave * 256 + 128 + nf * 16 + lane] = s2[nf];
            }
        }
        __syncthreads();
        if (tid < 128) {
            const float ss = red[tid] + red[256 + tid] + red[512 + tid] + red[768 + tid];
            const float qq = red[128 + tid] + red[384 + tid] + red[640 + tid] + red[896 + tid];
            atomicAdd(sbuf + tid, ss);
            atomicAdd(sbuf + FEAT + tid, qq);
        }
    }
}

// ============ CSR build ============
__global__ void hist_kernel(const int* __restrict__ dst, int* __restrict__ cnt) {
    const int e = blockIdx.x * blockDim.x + threadIdx.x;
    if (e < E_EDGES) atomicAdd(cnt + dst[e], 1);
}

// ---- hierarchical scan, phase 1: per-block (1024 elems) exclusive scan ----
__global__ __launch_bounds__(256)
void scan1(const int* __restrict__ cnt, int* __restrict__ rowptr, int* __restrict__ bsum) {
    __shared__ int lds[256];
    const int b = blockIdx.x, t = threadIdx.x;
    const int base = b * 1024 + t * 4;
    int v[4];
    #pragma unroll
    for (int i = 0; i < 4; ++i) v[i] = (base + i < N_NODES) ? cnt[base + i] : 0;
    lds[t] = v[0] + v[1] + v[2] + v[3];
    __syncthreads();
    for (int off = 1; off < 256; off <<= 1) {
        const int u = (t >= off) ? lds[t - off] : 0;
        __syncthreads();
        lds[t] += u;
        __syncthreads();
    }
    int excl = t ? lds[t - 1] : 0;
    if (t == 255) bsum[b] = lds[255];
    #pragma unroll
    for (int i = 0; i < 4; ++i) {
        if (base + i < N_NODES) rowptr[base + i] = excl;
        excl += v[i];
    }
}

// ---- phase 2: one wave scans the 49 block sums ----
__global__ void scan2(const int* __restrict__ bsum, int* __restrict__ boff,
                      int* __restrict__ rowptr) {
    const int lane = threadIdx.x;   // 64
    const int v = (lane < NB1) ? bsum[lane] : 0;
    int incl = v;
    #pragma unroll
    for (int off = 1; off < 64; off <<= 1) {
        const int u = __shfl_up(incl, off);
        if (lane >= off) incl += u;
    }
    if (lane < NB1) boff[lane] = incl - v;
    if (lane == 0) rowptr[N_NODES] = E_EDGES;
}

// ---- phase 3: add block offsets; seed cursor = rowptr ----
__global__ void scan3(int* __restrict__ rowptr, int* __restrict__ cursor,
                      const int* __restrict__ boff) {
    const int i = blockIdx.x * blockDim.x + threadIdx.x;
    if (i >= N_NODES) return;
    const int v = rowptr[i] + boff[i >> 10];
    rowptr[i] = v;
    cursor[i] = v;
}

// fill CSR slots with packed (order<<16)|src and dst (row id)
__global__ void fill_csr(const int* __restrict__ src, const int* __restrict__ dst,
                         const int* __restrict__ order,
                         int* __restrict__ cursor,
                         int* __restrict__ sord_p, int* __restrict__ dst_p) {
    const int e = blockIdx.x * blockDim.x + threadIdx.x;
    if (e >= E_EDGES) return;
    const int d = dst[e];
    const int pos = atomicAdd(cursor + d, 1);
    sord_p[pos] = (order[e] << 16) | src[e];
    dst_p[pos] = d;
}

// ---- per-edge (CSR order): attention logit + inv-dist, all streams ----
__global__ void edge_att(const float4* __restrict__ pk,
                         const int* __restrict__ sord_p,
                         const int* __restrict__ dst_p,
                         float* __restrict__ att_p,
                         float* __restrict__ invd_p) {
    const int e = blockIdx.x * blockDim.x + threadIdx.x;
    if (e >= E_EDGES) return;
    const int s = sord_p[e] & 0xFFFF;
    const int d = dst_p[e];
    const float4 a0 = pk[2 * s], a1 = pk[2 * s + 1], b0 = pk[2 * d];
    const float dx = a0.x - b0.x, dy = a0.y - b0.y, dz = a0.z - b0.z;
    att_p[e]  = dx * a0.w + dy * a1.x + dz * a1.y;
    invd_p[e] = 1.f / (dx * dx + dy * dy + dz * dz + 1.f);
}

// ---- fused segment softmax + gather-aggregate (one wave / node) ----
__global__ void segagg(const float* __restrict__ att_p,
                       const float* __restrict__ invd_p,
                       const int* __restrict__ sord_p,
                       const int* __restrict__ rowptr,
                       const unsigned short* __restrict__ xk,
                       unsigned short* __restrict__ hb) {
    const int node = (blockIdx.x * blockDim.x + threadIdx.x) >> 6;
    const int lane = threadIdx.x & 63;
    if (node >= N_NODES) return;
    const int beg = rowptr[node], end = rowptr[node + 1];

    float m = -3.402823e38f;
    for (int p = beg + lane; p < end; p += 64) m = fmaxf(m, att_p[p]);
    #pragma unroll
    for (int off = 32; off; off >>= 1) m = fmaxf(m, __shfl_xor(m, off));
    float s = 0.f;
    for (int p = beg + lane; p < end; p += 64) s += __expf(att_p[p] - m);
    #pragma unroll
    for (int off = 32; off; off >>= 1) s += __shfl_xor(s, off);
    const float inv_s = 1.f / (s > 0.f ? s : 1.f);

    float ax = 0.f, ay = 0.f;
    for (int cb = beg; cb < end; cb += 64) {
        const int p = cb + lane;
        float wl = 0.f;
        int sol = 0;
        if (p < end) {
            wl = __expf(att_p[p] - m) * inv_s * invd_p[p];
            sol = sord_p[p];
        }
        const int ne = min(64, end - cb);
        int j = 0;
        for (; j + 4 <= ne; j += 4) {
            const float w0 = __shfl(wl, j),     w1 = __shfl(wl, j + 1);
            const float w2 = __shfl(wl, j + 2), w3 = __shfl(wl, j + 3);
            const int so0 = __shfl(sol, j),     so1 = __shfl(sol, j + 1);
            const int so2 = __shfl(sol, j + 2), so3 = __shfl(sol, j + 3);
            const unsigned v0 = *(const unsigned*)(xk + (((size_t)(so0 >> 16) * N_NODES + (so0 & 0xFFFF)) << 7) + lane * 2);
            const unsigned v1 = *(const unsigned*)(xk + (((size_t)(so1 >> 16) * N_NODES + (so1 & 0xFFFF)) << 7) + lane * 2);
            const unsigned v2 = *(const unsigned*)(xk + (((size_t)(so2 >> 16) * N_NODES + (so2 & 0xFFFF)) << 7) + lane * 2);
            const unsigned v3 = *(const unsigned*)(xk + (((size_t)(so3 >> 16) * N_NODES + (so3 & 0xFFFF)) << 7) + lane * 2);
            ax = fmaf(w0, bflo(v0), ax); ay = fmaf(w0, bfhi(v0), ay);
            ax = fmaf(w1, bflo(v1), ax); ay = fmaf(w1, bfhi(v1), ay);
            ax = fmaf(w2, bflo(v2), ax); ay = fmaf(w2, bfhi(v2), ay);
            ax = fmaf(w3, bflo(v3), ax); ay = fmaf(w3, bfhi(v3), ay);
        }
        for (; j < ne; ++j) {
            const float w = __shfl(wl, j);
            const int so = __shfl(sol, j);
            const unsigned v = *(const unsigned*)(xk + (((size_t)(so >> 16) * N_NODES + (so & 0xFFFF)) << 7) + lane * 2);
            ax = fmaf(w, bflo(v), ax); ay = fmaf(w, bfhi(v), ay);
        }
    }
    *(unsigned*)(hb + ((size_t)node << 7) + lane * 2) =
        (unsigned)f2bf(ax) | ((unsigned)f2bf(ay) << 16);
}

// ---- mean/var -> scale/shift ----
__global__ void finalize(const float* __restrict__ sbuf,
                         const float* __restrict__ gamma,
                         const float* __restrict__ beta,
                         float* __restrict__ ss) {
    const int o = threadIdx.x;
    const float mean = sbuf[o] / (float)N_NODES;
    const float var  = sbuf[FEAT + o] / (float)N_NODES - mean * mean;
    const float sc   = gamma[o] * rsqrtf(var + BN_EPS);
    ss[o] = sc;
    ss[FEAT + o] = beta[o] - mean * sc;
}

// ---- out = out*scale + shift (in place, float4) ----
__global__ void normalize(float* __restrict__ y, const float* __restrict__ ss) {
    const int idx = blockIdx.x * blockDim.x + threadIdx.x;
    const int o4 = (idx & 31) * 4;
    float4 v = *(float4*)(y + (size_t)idx * 4);
    const float4 sc = *(const float4*)(ss + o4);
    const float4 sh = *(const float4*)(ss + FEAT + o4);
    v.x = fmaf(v.x, sc.x, sh.x);
    v.y = fmaf(v.y, sc.y, sh.y);
    v.z = fmaf(v.z, sc.z, sh.z);
    v.w = fmaf(v.w, sc.w, sh.w);
    *(float4*)(y + (size_t)idx * 4) = v;
}

extern "C" void kernel_launch(void* const* d_in, const int* in_sizes, int n_in,
                              void* d_out, int out_size, void* d_ws, size_t ws_size,
                              hipStream_t stream) {
    const float* feature = (const float*)d_in[0];
    const float* coords  = (const float*)d_in[1];
    const int*   src     = (const int*)d_in[2];
    const int*   dst     = (const int*)d_in[3];
    const int*   order   = (const int*)d_in[4];
    const float* linear  = (const float*)d_in[5];
    const float* attW    = (const float*)d_in[6];
    const float* mlp_w   = (const float*)d_in[7];
    const float* mlp_b   = (const float*)d_in[8];
    const float* gamma   = (const float*)d_in[9];
    const float* beta    = (const float*)d_in[10];
    float* out = (float*)d_out;

    char* p = (char*)d_ws;
    unsigned short* xk   = (unsigned short*)p; p += (size_t)KORD * N_NODES * FEAT * 2;  // 38.4 MB
    unsigned short* fb   = (unsigned short*)p; p += (size_t)N_NODES * FEAT * 2;         // 12.8 MB
    unsigned short* hb   = (unsigned short*)p; p += (size_t)N_NODES * FEAT * 2;         // 12.8 MB
    unsigned short* linT = (unsigned short*)p; p += (size_t)KORD * FEAT * FEAT * 2;     // 98 KB
    unsigned short* Wb   = (unsigned short*)p; p += (size_t)FEAT * FEAT * 2;            // 32 KB
    float4* pk           = (float4*)p;         p += (size_t)N_NODES * 32;               // 1.6 MB
    float* att_p         = (float*)p;          p += (size_t)E_EDGES * 4;
    float* invd_p        = (float*)p;          p += (size_t)E_EDGES * 4;
    int*   sord_p        = (int*)p;            p += (size_t)E_EDGES * 4;
    int*   dst_p         = (int*)p;            p += (size_t)E_EDGES * 4;
    int*   cnt           = (int*)p;            p += 200064;
    float* sbuf          = (float*)p;          p += 1024;    // memset covers cnt+sbuf
    int*   rowptr        = (int*)p;            p += 200064;
    int*   cursor        = (int*)p;            p += 200064;
    int*   bsum          = (int*)p;            p += 256;
    int*   boff          = (int*)p;            p += 256;
    float* ss            = (float*)p;          p += 1024;

    hipMemsetAsync(cnt, 0, 200064 + 1024, stream);

    const int EB  = (E_EDGES + 255) / 256;        // 3125
    const int NWB = (N_NODES * 64) / 256;         // 12500
    const int MB  = (N_NODES + 127) / 128;        // 391

    wcast  <<<64, 256, 0, stream>>>(mlp_w, Wb);
    lincast<<<KORD * FEAT, FEAT, 0, stream>>>(linear, linT);
    g_cast <<<NWB, 256, 0, stream>>>(feature, coords, attW, fb, pk);

    gemm_mfma<false><<<dim3(MB, KORD), 256, 0, stream>>>(fb, linT, xk, N_NODES, nullptr, nullptr);

    hist_kernel<<<EB, 256, 0, stream>>>(dst, cnt);
    scan1<<<NB1, 256, 0, stream>>>(cnt, rowptr, bsum);
    scan2<<<1, 64, 0, stream>>>(bsum, boff, rowptr);
    scan3<<<(N_NODES + 255) / 256, 256, 0, stream>>>(rowptr, cursor, boff);
    fill_csr<<<EB, 256, 0, stream>>>(src, dst, order, cursor, sord_p, dst_p);

    edge_att<<<EB, 256, 0, stream>>>(pk, sord_p, dst_p, att_p, invd_p);
    segagg<<<NWB, 256, 0, stream>>>(att_p, invd_p, sord_p, rowptr, xk, hb);

    gemm_mfma<true><<<dim3(MB, 1), 256, 0, stream>>>(hb, Wb, out, N_NODES, mlp_b, sbuf);
    finalize<<<1, FEAT, 0, stream>>>(sbuf, gamma, beta, ss);
    normalize<<<(N_NODES * 32) / 256, 256, 0, stream>>>(out, ss);
}

// Round 7
// 212.506 us; speedup vs baseline: 7.3678x; 1.1077x over previous
//
#include <hip/hip_runtime.h>

#define N_NODES 50000
#define E_EDGES 800000
#define FEAT    128
#define KORD    3
#define BN_EPS  1e-5f
#define NB1     49          // ceil(50000/1024) scan blocks
#define NBUK    49          // coarse buckets (dst >> 10)
#define BCAP    20480       // bucket capacity (mean 16.3K + 33 sigma)

typedef __attribute__((ext_vector_type(8))) short bf16x8;
typedef __attribute__((ext_vector_type(4))) float f32x4;

__device__ __forceinline__ unsigned short f2bf(float f) {   // RNE f32->bf16
    unsigned u = __float_as_uint(f);
    u += 0x7FFFu + ((u >> 16) & 1u);
    return (unsigned short)(u >> 16);
}
__device__ __forceinline__ float bflo(unsigned u) { return __uint_as_float(u << 16); }
__device__ __forceinline__ float bfhi(unsigned u) { return __uint_as_float(u & 0xFFFF0000u); }

// ---- mlp_w [o][i] f32 -> bf16 ----
__global__ void wcast(const float* __restrict__ W, unsigned short* __restrict__ Wb) {
    const int i = blockIdx.x * 256 + threadIdx.x;
    Wb[i] = f2bf(W[i]);
}

// ---- linT[k][o][i] = bf16(linear[k][i][o]) ----
__global__ void lincast(const float* __restrict__ L, unsigned short* __restrict__ Lt) {
    const int k = blockIdx.x >> 7;
    const int o = blockIdx.x & 127;
    const int i = threadIdx.x;
    Lt[((size_t)k * FEAT + o) * FEAT + i] = f2bf(L[((size_t)k * FEAT + i) * FEAT + o]);
}

// ---- per node: feature->bf16, and pack {coords, g=attW@f} into 2 float4 ----
__global__ void g_cast(const float* __restrict__ feat,
                       const float* __restrict__ coords,
                       const float* __restrict__ attW,
                       unsigned short* __restrict__ fb,
                       float4* __restrict__ pk) {
    const int node = (blockIdx.x * blockDim.x + threadIdx.x) >> 6;
    const int lane = threadIdx.x & 63;
    if (node >= N_NODES) return;
    const float2 f = *(const float2*)(feat + (size_t)node * FEAT + lane * 2);
    *(unsigned*)(fb + (size_t)node * FEAT + lane * 2) =
        (unsigned)f2bf(f.x) | ((unsigned)f2bf(f.y) << 16);
    float gg[3];
    #pragma unroll
    for (int j = 0; j < 3; ++j) {
        float p = f.x * attW[j * FEAT + lane * 2] + f.y * attW[j * FEAT + lane * 2 + 1];
        #pragma unroll
        for (int off = 32; off; off >>= 1) p += __shfl_xor(p, off);
        gg[j] = p;
    }
    if (lane == 0) {
        const float c0 = coords[node * 3 + 0], c1 = coords[node * 3 + 1], c2 = coords[node * 3 + 2];
        pk[2 * node]     = make_float4(c0, c1, c2, gg[0]);
        pk[2 * node + 1] = make_float4(gg[1], gg[2], 0.f, 0.f);
    }
}

// ============================================================================
// bf16 MFMA GEMM, K=N=128 fixed: C[m,o] = sum_i A[m,i]*B^T[o,i]
// ============================================================================
template<bool EPI>
__global__ __launch_bounds__(256)
void gemm_mfma(const unsigned short* __restrict__ A,
               const unsigned short* __restrict__ B_,
               void* __restrict__ C_, int M,
               const float* __restrict__ bias, float* __restrict__ sbuf) {
    __shared__ char smem[65536];
    const int kb = blockIdx.y;
    const unsigned short* B = B_ + (size_t)kb * FEAT * FEAT;
    const size_t c_off = (size_t)kb * (size_t)M * FEAT;
    const int m0 = blockIdx.x * 128;
    const int tid = threadIdx.x;

    for (int p = tid; p < 2048; p += 256) {
        const int row = p >> 4, chunk = p & 15;
        const int off = ((row << 8) + (chunk << 4)) ^ ((row & 7) << 4);
        float4 va = make_float4(0.f, 0.f, 0.f, 0.f);
        if (m0 + row < M) va = *(const float4*)(A + (size_t)(m0 + row) * FEAT + chunk * 8);
        *(float4*)(smem + off) = va;
        *(float4*)(smem + 32768 + off) = *(const float4*)(B + (size_t)row * FEAT + chunk * 8);
    }
    __syncthreads();

    const int wave = tid >> 6, lane = tid & 63;
    const int wm0 = wave * 32;
    const int lrow = lane & 15;
    const int kslot = (lane >> 4) << 4;
    const int swz = (lrow & 7) << 4;

    f32x4 acc[2][8];
    #pragma unroll
    for (int a = 0; a < 2; ++a)
        #pragma unroll
        for (int b = 0; b < 8; ++b) acc[a][b] = (f32x4){0.f, 0.f, 0.f, 0.f};

    bf16x8 afr[2][4];
    #pragma unroll
    for (int mf = 0; mf < 2; ++mf)
        #pragma unroll
        for (int ks = 0; ks < 4; ++ks) {
            const int row = wm0 + mf * 16 + lrow;
            afr[mf][ks] = *(const bf16x8*)(smem + (((row << 8) + (ks << 6) + kslot) ^ swz));
        }
    #pragma unroll
    for (int nf = 0; nf < 8; ++nf) {
        #pragma unroll
        for (int ks = 0; ks < 4; ++ks) {
            const int row = nf * 16 + lrow;
            bf16x8 bfr = *(const bf16x8*)(smem + 32768 + (((row << 8) + (ks << 6) + kslot) ^ swz));
            acc[0][nf] = __builtin_amdgcn_mfma_f32_16x16x32_bf16(afr[0][ks], bfr, acc[0][nf], 0, 0, 0);
            acc[1][nf] = __builtin_amdgcn_mfma_f32_16x16x32_bf16(afr[1][ks], bfr, acc[1][nf], 0, 0, 0);
        }
    }

    if (!EPI) {
        __syncthreads();
        float* Cs = (float*)smem;
        #pragma unroll
        for (int mf = 0; mf < 2; ++mf)
            #pragma unroll
            for (int nf = 0; nf < 8; ++nf)
                #pragma unroll
                for (int rg = 0; rg < 4; ++rg)
                    Cs[(wm0 + mf * 16 + (lane >> 4) * 4 + rg) * 128 + nf * 16 + lrow] = acc[mf][nf][rg];
        __syncthreads();
        unsigned short* Cb = (unsigned short*)C_ + c_off;
        const int r = tid >> 1, half = tid & 1;
        if (m0 + r < M) {
            const float* srcp = Cs + r * 128 + half * 64;
            #pragma unroll
            for (int j = 0; j < 64; j += 8) {
                unsigned short tmp[8];
                #pragma unroll
                for (int q = 0; q < 8; ++q) tmp[q] = f2bf(srcp[j + q]);
                *(uint4*)(Cb + (size_t)(m0 + r) * FEAT + half * 64 + j) = *(uint4*)tmp;
            }
        }
    } else {
        float* C = (float*)C_ + c_off;
        float s[8], s2[8], bv[8];
        #pragma unroll
        for (int nf = 0; nf < 8; ++nf) { s[nf] = 0.f; s2[nf] = 0.f; bv[nf] = bias[nf * 16 + lrow]; }
        #pragma unroll
        for (int mf = 0; mf < 2; ++mf)
            #pragma unroll
            for (int nf = 0; nf < 8; ++nf)
                #pragma unroll
                for (int rg = 0; rg < 4; ++rg) {
                    const int row = m0 + wm0 + mf * 16 + (lane >> 4) * 4 + rg;
                    if (row < M) {
                        const float v = fmaxf(acc[mf][nf][rg] + bv[nf], 0.f);
                        C[(size_t)row * FEAT + nf * 16 + lrow] = v;
                        s[nf] += v;
                        s2[nf] = fmaf(v, v, s2[nf]);
                    }
                }
        #pragma unroll
        for (int nf = 0; nf < 8; ++nf) {
            s[nf]  += __shfl_xor(s[nf], 16);  s[nf]  += __shfl_xor(s[nf], 32);
            s2[nf] += __shfl_xor(s2[nf], 16); s2[nf] += __shfl_xor(s2[nf], 32);
        }
        __syncthreads();
        float* red = (float*)smem;
        if (lane < 16) {
            #pragma unroll
            for (int nf = 0; nf < 8; ++nf) {
                red[wave * 256 + nf * 16 + lane]       = s[nf];
                red[wave * 256 + 128 + nf * 16 + lane] = s2[nf];
            }
        }
        __syncthreads();
        if (tid < 128) {
            const float ss = red[tid] + red[256 + tid] + red[512 + tid] + red[768 + tid];
            const float qq = red[128 + tid] + red[384 + tid] + red[640 + tid] + red[896 + tid];
            atomicAdd(sbuf + tid, ss);
            atomicAdd(sbuf + FEAT + tid, qq);
        }
    }
}

// ============ CSR build ============
__global__ void hist_kernel(const int* __restrict__ dst, int* __restrict__ cnt) {
    const int e = blockIdx.x * blockDim.x + threadIdx.x;
    if (e < E_EDGES) atomicAdd(cnt + dst[e], 1);
}

__global__ __launch_bounds__(256)
void scan1(const int* __restrict__ cnt, int* __restrict__ rowptr, int* __restrict__ bsum) {
    __shared__ int lds[256];
    const int b = blockIdx.x, t = threadIdx.x;
    const int base = b * 1024 + t * 4;
    int v[4];
    #pragma unroll
    for (int i = 0; i < 4; ++i) v[i] = (base + i < N_NODES) ? cnt[base + i] : 0;
    lds[t] = v[0] + v[1] + v[2] + v[3];
    __syncthreads();
    for (int off = 1; off < 256; off <<= 1) {
        const int u = (t >= off) ? lds[t - off] : 0;
        __syncthreads();
        lds[t] += u;
        __syncthreads();
    }
    int excl = t ? lds[t - 1] : 0;
    if (t == 255) bsum[b] = lds[255];
    #pragma unroll
    for (int i = 0; i < 4; ++i) {
        if (base + i < N_NODES) rowptr[base + i] = excl;
        excl += v[i];
    }
}

__global__ void scan2(const int* __restrict__ bsum, int* __restrict__ boff,
                      int* __restrict__ rowptr) {
    const int lane = threadIdx.x;   // 64
    const int v = (lane < NB1) ? bsum[lane] : 0;
    int incl = v;
    #pragma unroll
    for (int off = 1; off < 64; off <<= 1) {
        const int u = __shfl_up(incl, off);
        if (lane >= off) incl += u;
    }
    if (lane < NB1) boff[lane] = incl - v;
    if (lane == 0) rowptr[N_NODES] = E_EDGES;
}

__global__ void scan3(int* __restrict__ rowptr, int* __restrict__ cursor,
                      const int* __restrict__ boff) {
    const int i = blockIdx.x * blockDim.x + threadIdx.x;
    if (i >= N_NODES) return;
    const int v = rowptr[i] + boff[i >> 10];
    rowptr[i] = v;
    cursor[i] = v;
}

// ---- bucket pass A: edges -> 49 coarse buckets, block-aggregated ----
__global__ __launch_bounds__(256)
void bucketA(const int* __restrict__ src, const int* __restrict__ dst,
             const int* __restrict__ order,
             int* __restrict__ gcur, int2* __restrict__ bbuf) {
    __shared__ int lcnt[NBUK];
    __shared__ int lbase[NBUK];
    const int tid = threadIdx.x;
    if (tid < NBUK) lcnt[tid] = 0;
    __syncthreads();
    const int e0 = blockIdx.x * 2048;
    int b[8], r[8], so[8], dd[8];
    #pragma unroll
    for (int i = 0; i < 8; ++i) {
        const int e = e0 + i * 256 + tid;
        if (e < E_EDGES) {
            dd[i] = dst[e];
            so[i] = (order[e] << 16) | src[e];
            b[i] = dd[i] >> 10;
            r[i] = atomicAdd(&lcnt[b[i]], 1);
        } else b[i] = -1;
    }
    __syncthreads();
    if (tid < NBUK) lbase[tid] = atomicAdd(&gcur[tid], lcnt[tid]);
    __syncthreads();
    #pragma unroll
    for (int i = 0; i < 8; ++i)
        if (b[i] >= 0)
            bbuf[(size_t)b[i] * BCAP + lbase[b[i]] + r[i]] = make_int2(so[i], dd[i]);
}

// ---- bucket pass B: bucket entries -> final CSR slots (L2-windowed scatter)
__global__ void bucketB(const int* __restrict__ gcur, const int2* __restrict__ bbuf,
                        int* __restrict__ cursor, int* __restrict__ sord_p) {
    const int b = blockIdx.x >> 3;
    const int seg = blockIdx.x & 7;
    const int n = gcur[b];
    const int lo = (int)((long)n * seg / 8), hi = (int)((long)n * (seg + 1) / 8);
    for (int i = lo + (int)threadIdx.x; i < hi; i += 256) {
        const int2 ent = bbuf[(size_t)b * BCAP + i];
        const int pos = atomicAdd(cursor + ent.y, 1);
        sord_p[pos] = ent.x;
    }
}

// ---- fused edge-att + segment softmax + gather-aggregate (one wave/node) ----
__global__ void segagg(const float4* __restrict__ pk,
                       const int* __restrict__ sord_p,
                       const int* __restrict__ rowptr,
                       const unsigned short* __restrict__ xk,
                       unsigned short* __restrict__ hb) {
    const int node = (blockIdx.x * blockDim.x + threadIdx.x) >> 6;
    const int lane = threadIdx.x & 63;
    if (node >= N_NODES) return;
    const int beg = rowptr[node], end = rowptr[node + 1];
    const float4 b0 = pk[2 * node];

    // online (m,s) over all edges; cache chunk-0 (deg<=64 covers ~all nodes)
    float att0 = -1e30f, inv0 = 0.f; int sol0 = 0;
    float m = -1e30f, s = 0.f;
    int nch = 0;
    for (int cb = beg; cb < end; cb += 64, ++nch) {
        const int p = cb + lane;
        float a = -1e30f, iv = 0.f; int so = 0;
        if (p < end) {
            so = sord_p[p];
            const int sn = so & 0xFFFF;
            const float4 a0 = pk[2 * sn], a1 = pk[2 * sn + 1];
            const float dx = a0.x - b0.x, dy = a0.y - b0.y, dz = a0.z - b0.z;
            a = dx * a0.w + dy * a1.x + dz * a1.y;
            iv = 1.f / (dx * dx + dy * dy + dz * dz + 1.f);
        }
        if (nch == 0) { att0 = a; inv0 = iv; sol0 = so; }
        const float mn = fmaxf(m, a);
        s = s * __expf(m - mn) + ((p < end) ? __expf(a - mn) : 0.f);
        m = mn;
    }
    #pragma unroll
    for (int off = 32; off; off >>= 1) {
        const float mo = __shfl_xor(m, off), so_ = __shfl_xor(s, off);
        const float mn = fmaxf(m, mo);
        s = s * __expf(m - mn) + so_ * __expf(mo - mn);
        m = mn;
    }
    const float inv_s = s > 0.f ? 1.f / s : 0.f;

    float ax = 0.f, ay = 0.f;
    int ch = 0;
    for (int cb = beg; cb < end; cb += 64, ++ch) {
        const int p = cb + lane;
        float wl = 0.f; int so = 0;
        if (ch == 0) {
            wl = __expf(att0 - m) * inv_s * inv0;   // dead lanes: exp(-1e30-m)=0
            so = sol0;
        } else if (p < end) {
            so = sord_p[p];
            const int sn = so & 0xFFFF;
            const float4 a0 = pk[2 * sn], a1 = pk[2 * sn + 1];
            const float dx = a0.x - b0.x, dy = a0.y - b0.y, dz = a0.z - b0.z;
            const float a = dx * a0.w + dy * a1.x + dz * a1.y;
            wl = __expf(a - m) * inv_s / (dx * dx + dy * dy + dz * dz + 1.f);
        }
        const int ne = min(64, end - cb);
        int j = 0;
        for (; j + 4 <= ne; j += 4) {
            const float w0 = __shfl(wl, j),     w1 = __shfl(wl, j + 1);
            const float w2 = __shfl(wl, j + 2), w3 = __shfl(wl, j + 3);
            const int so0 = __shfl(so, j),      so1 = __shfl(so, j + 1);
            const int so2 = __shfl(so, j + 2),  so3 = __shfl(so, j + 3);
            const unsigned v0 = *(const unsigned*)(xk + (((size_t)(so0 >> 16) * N_NODES + (so0 & 0xFFFF)) << 7) + lane * 2);
            const unsigned v1 = *(const unsigned*)(xk + (((size_t)(so1 >> 16) * N_NODES + (so1 & 0xFFFF)) << 7) + lane * 2);
            const unsigned v2 = *(const unsigned*)(xk + (((size_t)(so2 >> 16) * N_NODES + (so2 & 0xFFFF)) << 7) + lane * 2);
            const unsigned v3 = *(const unsigned*)(xk + (((size_t)(so3 >> 16) * N_NODES + (so3 & 0xFFFF)) << 7) + lane * 2);
            ax = fmaf(w0, bflo(v0), ax); ay = fmaf(w0, bfhi(v0), ay);
            ax = fmaf(w1, bflo(v1), ax); ay = fmaf(w1, bfhi(v1), ay);
            ax = fmaf(w2, bflo(v2), ax); ay = fmaf(w2, bfhi(v2), ay);
            ax = fmaf(w3, bflo(v3), ax); ay = fmaf(w3, bfhi(v3), ay);
        }
        for (; j < ne; ++j) {
            const float w = __shfl(wl, j);
            const int soj = __shfl(so, j);
            const unsigned v = *(const unsigned*)(xk + (((size_t)(soj >> 16) * N_NODES + (soj & 0xFFFF)) << 7) + lane * 2);
            ax = fmaf(w, bflo(v), ax); ay = fmaf(w, bfhi(v), ay);
        }
    }
    *(unsigned*)(hb + ((size_t)node << 7) + lane * 2) =
        (unsigned)f2bf(ax) | ((unsigned)f2bf(ay) << 16);
}

// ---- mean/var -> scale/shift ----
__global__ void finalize(const float* __restrict__ sbuf,
                         const float* __restrict__ gamma,
                         const float* __restrict__ beta,
                         float* __restrict__ ss) {
    const int o = threadIdx.x;
    const float mean = sbuf[o] / (float)N_NODES;
    const float var  = sbuf[FEAT + o] / (float)N_NODES - mean * mean;
    const float sc   = gamma[o] * rsqrtf(var + BN_EPS);
    ss[o] = sc;
    ss[FEAT + o] = beta[o] - mean * sc;
}

// ---- out = out*scale + shift (in place, float4) ----
__global__ void normalize(float* __restrict__ y, const float* __restrict__ ss) {
    const int idx = blockIdx.x * blockDim.x + threadIdx.x;
    const int o4 = (idx & 31) * 4;
    float4 v = *(float4*)(y + (size_t)idx * 4);
    const float4 sc = *(const float4*)(ss + o4);
    const float4 sh = *(const float4*)(ss + FEAT + o4);
    v.x = fmaf(v.x, sc.x, sh.x);
    v.y = fmaf(v.y, sc.y, sh.y);
    v.z = fmaf(v.z, sc.z, sh.z);
    v.w = fmaf(v.w, sc.w, sh.w);
    *(float4*)(y + (size_t)idx * 4) = v;
}

extern "C" void kernel_launch(void* const* d_in, const int* in_sizes, int n_in,
                              void* d_out, int out_size, void* d_ws, size_t ws_size,
                              hipStream_t stream) {
    const float* feature = (const float*)d_in[0];
    const float* coords  = (const float*)d_in[1];
    const int*   src     = (const int*)d_in[2];
    const int*   dst     = (const int*)d_in[3];
    const int*   order   = (const int*)d_in[4];
    const float* linear  = (const float*)d_in[5];
    const float* attW    = (const float*)d_in[6];
    const float* mlp_w   = (const float*)d_in[7];
    const float* mlp_b   = (const float*)d_in[8];
    const float* gamma   = (const float*)d_in[9];
    const float* beta    = (const float*)d_in[10];
    float* out = (float*)d_out;

    char* p = (char*)d_ws;
    unsigned short* xk   = (unsigned short*)p; p += (size_t)KORD * N_NODES * FEAT * 2;  // 38.4 MB
    unsigned short* fb   = (unsigned short*)p; p += (size_t)N_NODES * FEAT * 2;         // 12.8 MB
    unsigned short* hb   = (unsigned short*)p; p += (size_t)N_NODES * FEAT * 2;         // 12.8 MB
    unsigned short* linT = (unsigned short*)p; p += (size_t)KORD * FEAT * FEAT * 2;     // 98 KB
    unsigned short* Wb   = (unsigned short*)p; p += (size_t)FEAT * FEAT * 2;            // 32 KB
    float4* pk           = (float4*)p;         p += (size_t)N_NODES * 32;               // 1.6 MB
    int*   sord_p        = (int*)p;            p += (size_t)E_EDGES * 4;                // 3.2 MB
    int2*  bbuf          = (int2*)p;           p += (size_t)NBUK * BCAP * 8;            // 8.0 MB
    int*   cnt           = (int*)p;            p += 200064;
    float* sbuf          = (float*)p;          p += 1024;
    int*   gcur          = (int*)p;            p += 1024;    // memset covers cnt+sbuf+gcur
    int*   rowptr        = (int*)p;            p += 200064;
    int*   cursor        = (int*)p;            p += 200064;
    int*   bsum          = (int*)p;            p += 256;
    int*   boff          = (int*)p;            p += 256;
    float* ss            = (float*)p;          p += 1024;

    hipMemsetAsync(cnt, 0, 200064 + 1024 + 1024, stream);

    const int EB  = (E_EDGES + 255) / 256;        // 3125
    const int NWB = (N_NODES * 64) / 256;         // 12500
    const int MB  = (N_NODES + 127) / 128;        // 391
    const int AB  = (E_EDGES + 2047) / 2048;      // 391

    wcast  <<<64, 256, 0, stream>>>(mlp_w, Wb);
    lincast<<<KORD * FEAT, FEAT, 0, stream>>>(linear, linT);
    g_cast <<<NWB, 256, 0, stream>>>(feature, coords, attW, fb, pk);

    gemm_mfma<false><<<dim3(MB, KORD), 256, 0, stream>>>(fb, linT, xk, N_NODES, nullptr, nullptr);

    hist_kernel<<<EB, 256, 0, stream>>>(dst, cnt);
    scan1<<<NB1, 256, 0, stream>>>(cnt, rowptr, bsum);
    scan2<<<1, 64, 0, stream>>>(bsum, boff, rowptr);
    scan3<<<(N_NODES + 255) / 256, 256, 0, stream>>>(rowptr, cursor, boff);

    bucketA<<<AB, 256, 0, stream>>>(src, dst, order, gcur, bbuf);
    bucketB<<<NBUK * 8, 256, 0, stream>>>(gcur, bbuf, cursor, sord_p);

    segagg<<<NWB, 256, 0, stream>>>(pk, sord_p, rowptr, xk, hb);

    gemm_mfma<true><<<dim3(MB, 1), 256, 0, stream>>>(hb, Wb, out, N_NODES, mlp_b, sbuf);
    finalize<<<1, FEAT, 0, stream>>>(sbuf, gamma, beta, ss);
    normalize<<<(N_NODES * 32) / 256, 256, 0, stream>>>(out, ss);
}

// Round 8
// 195.106 us; speedup vs baseline: 8.0249x; 1.0892x over previous
//
#include <hip/hip_runtime.h>

#define N_NODES 50000
#define E_EDGES 800000
#define FEAT    128
#define KORD    3
#define BN_EPS  1e-5f
#define NB1     49          // ceil(50000/1024) scan blocks
#define NBUK    49          // coarse buckets (dst >> 10)
#define BCAP    20480       // bucket capacity

typedef __attribute__((ext_vector_type(8))) short bf16x8;
typedef __attribute__((ext_vector_type(4))) float f32x4;

__device__ __forceinline__ unsigned short f2bf(float f) {   // RNE f32->bf16
    unsigned u = __float_as_uint(f);
    u += 0x7FFFu + ((u >> 16) & 1u);
    return (unsigned short)(u >> 16);
}
__device__ __forceinline__ float bflo(unsigned u) { return __uint_as_float(u << 16); }
__device__ __forceinline__ float bfhi(unsigned u) { return __uint_as_float(u & 0xFFFF0000u); }

// ---- weights prep: Wb[o][i]=bf16(W[o][i]);  LtT[o][k*128+i]=bf16(L[k][i][o]) ----
__global__ void wprep(const float* __restrict__ W, const float* __restrict__ L,
                      unsigned short* __restrict__ Wb, unsigned short* __restrict__ LtT) {
    const int o = blockIdx.x;      // 128
    const int i = threadIdx.x;     // 128
    Wb[o * FEAT + i] = f2bf(W[o * FEAT + i]);
    #pragma unroll
    for (int k = 0; k < KORD; ++k)
        LtT[(size_t)o * 384 + k * FEAT + i] = f2bf(L[((size_t)k * FEAT + i) * FEAT + o]);
}

// ---- per node: feature->bf16, and pack {coords, g=attW@f} into 2 float4 ----
__global__ void g_cast(const float* __restrict__ feat,
                       const float* __restrict__ coords,
                       const float* __restrict__ attW,
                       unsigned short* __restrict__ fb,
                       float4* __restrict__ pk) {
    const int node = (blockIdx.x * blockDim.x + threadIdx.x) >> 6;
    const int lane = threadIdx.x & 63;
    if (node >= N_NODES) return;
    const float2 f = *(const float2*)(feat + (size_t)node * FEAT + lane * 2);
    *(unsigned*)(fb + (size_t)node * FEAT + lane * 2) =
        (unsigned)f2bf(f.x) | ((unsigned)f2bf(f.y) << 16);
    float gg[3];
    #pragma unroll
    for (int j = 0; j < 3; ++j) {
        float p = f.x * attW[j * FEAT + lane * 2] + f.y * attW[j * FEAT + lane * 2 + 1];
        #pragma unroll
        for (int off = 32; off; off >>= 1) p += __shfl_xor(p, off);
        gg[j] = p;
    }
    if (lane == 0) {
        const float c0 = coords[node * 3 + 0], c1 = coords[node * 3 + 1], c2 = coords[node * 3 + 2];
        pk[2 * node]     = make_float4(c0, c1, c2, gg[0]);
        pk[2 * node + 1] = make_float4(gg[1], gg[2], 0.f, 0.f);
    }
}

// ============ CSR build ============
// bucket pass A (+ fused per-node histogram)
__global__ __launch_bounds__(256)
void bucketA(const int* __restrict__ src, const int* __restrict__ dst,
             const int* __restrict__ order,
             int* __restrict__ cnt, int* __restrict__ gcur, int2* __restrict__ bbuf) {
    __shared__ int lcnt[NBUK];
    __shared__ int lbase[NBUK];
    const int tid = threadIdx.x;
    if (tid < NBUK) lcnt[tid] = 0;
    __syncthreads();
    const int e0 = blockIdx.x * 2048;
    int b[8], r[8], so[8], dd[8];
    #pragma unroll
    for (int i = 0; i < 8; ++i) {
        const int e = e0 + i * 256 + tid;
        if (e < E_EDGES) {
            dd[i] = dst[e];
            so[i] = (order[e] << 16) | src[e];
            b[i] = dd[i] >> 10;
            r[i] = atomicAdd(&lcnt[b[i]], 1);
            atomicAdd(cnt + dd[i], 1);
        } else b[i] = -1;
    }
    __syncthreads();
    if (tid < NBUK) lbase[tid] = atomicAdd(&gcur[tid], lcnt[tid]);
    __syncthreads();
    #pragma unroll
    for (int i = 0; i < 8; ++i)
        if (b[i] >= 0)
            bbuf[(size_t)b[i] * BCAP + lbase[b[i]] + r[i]] = make_int2(so[i], dd[i]);
}

__global__ __launch_bounds__(256)
void scan1(const int* __restrict__ cnt, int* __restrict__ rowptr, int* __restrict__ bsum) {
    __shared__ int lds[256];
    const int b = blockIdx.x, t = threadIdx.x;
    const int base = b * 1024 + t * 4;
    int v[4];
    #pragma unroll
    for (int i = 0; i < 4; ++i) v[i] = (base + i < N_NODES) ? cnt[base + i] : 0;
    lds[t] = v[0] + v[1] + v[2] + v[3];
    __syncthreads();
    for (int off = 1; off < 256; off <<= 1) {
        const int u = (t >= off) ? lds[t - off] : 0;
        __syncthreads();
        lds[t] += u;
        __syncthreads();
    }
    int excl = t ? lds[t - 1] : 0;
    if (t == 255) bsum[b] = lds[255];
    #pragma unroll
    for (int i = 0; i < 4; ++i) {
        if (base + i < N_NODES) rowptr[base + i] = excl;
        excl += v[i];
    }
}

__global__ void scan2(const int* __restrict__ bsum, int* __restrict__ boff,
                      int* __restrict__ rowptr) {
    const int lane = threadIdx.x;   // 64
    const int v = (lane < NB1) ? bsum[lane] : 0;
    int incl = v;
    #pragma unroll
    for (int off = 1; off < 64; off <<= 1) {
        const int u = __shfl_up(incl, off);
        if (lane >= off) incl += u;
    }
    if (lane < NB1) boff[lane] = incl - v;
    if (lane == 0) rowptr[N_NODES] = E_EDGES;
}

__global__ void scan3(int* __restrict__ rowptr, int* __restrict__ cursor,
                      const int* __restrict__ boff) {
    const int i = blockIdx.x * blockDim.x + threadIdx.x;
    if (i >= N_NODES) return;
    const int v = rowptr[i] + boff[i >> 10];
    rowptr[i] = v;
    cursor[i] = v;
}

// bucket pass B: bucket entries -> final CSR slots (L2-windowed scatter)
__global__ void bucketB(const int* __restrict__ gcur, const int2* __restrict__ bbuf,
                        int* __restrict__ cursor, int* __restrict__ sord_p) {
    const int b = blockIdx.x >> 3;
    const int seg = blockIdx.x & 7;
    const int n = gcur[b];
    const int lo = (int)((long)n * seg / 8), hi = (int)((long)n * (seg + 1) / 8);
    for (int i = lo + (int)threadIdx.x; i < hi; i += 256) {
        const int2 ent = bbuf[(size_t)b * BCAP + i];
        const int pos = atomicAdd(cursor + ent.y, 1);
        sord_p[pos] = ent.x;
    }
}

// ---- fused edge-att + segment softmax + per-order gather-aggregate ----
// agg[n][k*128+i] = sum_{e in CSR[n], order=k} w_e * f[src_e, i]   (bf16 out)
__global__ void segagg(const float4* __restrict__ pk,
                       const int* __restrict__ sord_p,
                       const int* __restrict__ rowptr,
                       const unsigned short* __restrict__ fb,
                       unsigned short* __restrict__ agg) {
    const int node = (blockIdx.x * blockDim.x + threadIdx.x) >> 6;
    const int lane = threadIdx.x & 63;
    if (node >= N_NODES) return;
    const int beg = rowptr[node], end = rowptr[node + 1];
    const float4 b0 = pk[2 * node];

    // phase 1: online (m,s); cache chunk-0 (deg<=64 covers ~all nodes)
    float att0 = -1e30f, inv0 = 0.f; int sol0 = 0;
    float m = -1e30f, s = 0.f;
    int nch = 0;
    for (int cb = beg; cb < end; cb += 64, ++nch) {
        const int p = cb + lane;
        float a = -1e30f, iv = 0.f; int so = 0;
        if (p < end) {
            so = sord_p[p];
            const int sn = so & 0xFFFF;
            const float4 a0 = pk[2 * sn], a1 = pk[2 * sn + 1];
            const float dx = a0.x - b0.x, dy = a0.y - b0.y, dz = a0.z - b0.z;
            a = dx * a0.w + dy * a1.x + dz * a1.y;
            iv = 1.f / (dx * dx + dy * dy + dz * dz + 1.f);
        }
        if (nch == 0) { att0 = a; inv0 = iv; sol0 = so; }
        const float mn = fmaxf(m, a);
        s = s * __expf(m - mn) + ((p < end) ? __expf(a - mn) : 0.f);
        m = mn;
    }
    #pragma unroll
    for (int off = 32; off; off >>= 1) {
        const float mo = __shfl_xor(m, off), so_ = __shfl_xor(s, off);
        const float mn = fmaxf(m, mo);
        s = s * __expf(m - mn) + so_ * __expf(mo - mn);
        m = mn;
    }
    const float inv_s = s > 0.f ? 1.f / s : 0.f;

    // phase 2: pair-gather. lanes 0-31: even edges, 32-63: odd edges; 4 feats/lane.
    const int half = lane >> 5;
    const int lsub = lane & 31;
    float a0c[4] = {0.f, 0.f, 0.f, 0.f};
    float a1c[4] = {0.f, 0.f, 0.f, 0.f};
    float a2c[4] = {0.f, 0.f, 0.f, 0.f};

    int ch = 0;
    for (int cb = beg; cb < end; cb += 64, ++ch) {
        const int p = cb + lane;
        float wl = 0.f; int so = 0;
        if (ch == 0) {
            wl = __expf(att0 - m) * inv_s * inv0;   // dead lanes: exp(-1e30)=0, inv0=0
            so = sol0;
        } else if (p < end) {
            so = sord_p[p];
            const int sn = so & 0xFFFF;
            const float4 a0 = pk[2 * sn], a1 = pk[2 * sn + 1];
            const float dx = a0.x - b0.x, dy = a0.y - b0.y, dz = a0.z - b0.z;
            const float a = dx * a0.w + dy * a1.x + dz * a1.y;
            wl = __expf(a - m) * inv_s / (dx * dx + dy * dy + dz * dz + 1.f);
        }
        const int ne = min(64, end - cb);
        for (int t = 0; t < ne; t += 2) {
            const float w  = __shfl(wl, t + half);   // lo half: edge t, hi half: edge t+1
            const int  soj = __shfl(so, t + half);   // (invalid odd tail has wl=0,so=0)
            const uint2 v = *(const uint2*)(fb + ((size_t)(soj & 0xFFFF) << 7) + lsub * 4);
            const float f0 = bflo(v.x), f1 = bfhi(v.x), f2 = bflo(v.y), f3 = bfhi(v.y);
            const int k = soj >> 16;
            if (k == 0) {
                a0c[0] = fmaf(w, f0, a0c[0]); a0c[1] = fmaf(w, f1, a0c[1]);
                a0c[2] = fmaf(w, f2, a0c[2]); a0c[3] = fmaf(w, f3, a0c[3]);
            } else if (k == 1) {
                a1c[0] = fmaf(w, f0, a1c[0]); a1c[1] = fmaf(w, f1, a1c[1]);
                a1c[2] = fmaf(w, f2, a1c[2]); a1c[3] = fmaf(w, f3, a1c[3]);
            } else {
                a2c[0] = fmaf(w, f0, a2c[0]); a2c[1] = fmaf(w, f1, a2c[1]);
                a2c[2] = fmaf(w, f2, a2c[2]); a2c[3] = fmaf(w, f3, a2c[3]);
            }
        }
    }
    // combine halves (lane l and l+32 hold the same 4 features)
    #pragma unroll
    for (int f = 0; f < 4; ++f) {
        a0c[f] += __shfl_xor(a0c[f], 32);
        a1c[f] += __shfl_xor(a1c[f], 32);
        a2c[f] += __shfl_xor(a2c[f], 32);
    }
    if (lane < 32) {
        unsigned short* row = agg + (size_t)node * 384 + lsub * 4;
        uint2 o0, o1, o2;
        o0.x = (unsigned)f2bf(a0c[0]) | ((unsigned)f2bf(a0c[1]) << 16);
        o0.y = (unsigned)f2bf(a0c[2]) | ((unsigned)f2bf(a0c[3]) << 16);
        o1.x = (unsigned)f2bf(a1c[0]) | ((unsigned)f2bf(a1c[1]) << 16);
        o1.y = (unsigned)f2bf(a1c[2]) | ((unsigned)f2bf(a1c[3]) << 16);
        o2.x = (unsigned)f2bf(a2c[0]) | ((unsigned)f2bf(a2c[1]) << 16);
        o2.y = (unsigned)f2bf(a2c[2]) | ((unsigned)f2bf(a2c[3]) << 16);
        *(uint2*)(row)       = o0;
        *(uint2*)(row + 128) = o1;
        *(uint2*)(row + 256) = o2;
    }
}

// ============================================================================
// Fused two-stage MFMA GEMM:
//   stage 1: h[m,o] = sum_{ki<384} agg[m,ki] * LtT[o,ki]     (K=384)
//   stage 2: y[m,o] = relu(sum_i bf16(h)[m,i] * Wb[o,i] + b) (K=128) + BN stats
// 256 thr (4 waves), 128-row tile, swizzled LDS (T2).
// ============================================================================
__global__ __launch_bounds__(256)
void fused_gemm(const unsigned short* __restrict__ agg,
                const unsigned short* __restrict__ LtT,
                const unsigned short* __restrict__ Wb,
                float* __restrict__ out, int M,
                const float* __restrict__ bias, float* __restrict__ sbuf) {
    __shared__ char smem[65536];
    const int m0 = blockIdx.x * 128;
    const int tid = threadIdx.x;
    const int wave = tid >> 6, lane = tid & 63;
    const int wm0 = wave * 32;
    const int lrow = lane & 15;
    const int kslot = (lane >> 4) << 4;
    const int swz = (lrow & 7) << 4;

    f32x4 acc[2][8];
    #pragma unroll
    for (int a = 0; a < 2; ++a)
        #pragma unroll
        for (int b = 0; b < 8; ++b) acc[a][b] = (f32x4){0.f, 0.f, 0.f, 0.f};

    // ---- stage 1: K=384 in three 128-chunks ----
    for (int kc = 0; kc < 3; ++kc) {
        __syncthreads();
        for (int p = tid; p < 2048; p += 256) {
            const int row = p >> 4, chunk = p & 15;
            const int off = ((row << 8) + (chunk << 4)) ^ ((row & 7) << 4);
            float4 va = make_float4(0.f, 0.f, 0.f, 0.f);
            if (m0 + row < M)
                va = *(const float4*)(agg + (size_t)(m0 + row) * 384 + kc * 128 + chunk * 8);
            *(float4*)(smem + off) = va;
            *(float4*)(smem + 32768 + off) =
                *(const float4*)(LtT + (size_t)row * 384 + kc * 128 + chunk * 8);
        }
        __syncthreads();
        bf16x8 afr[2][4];
        #pragma unroll
        for (int mf = 0; mf < 2; ++mf)
            #pragma unroll
            for (int ks = 0; ks < 4; ++ks) {
                const int row = wm0 + mf * 16 + lrow;
                afr[mf][ks] = *(const bf16x8*)(smem + (((row << 8) + (ks << 6) + kslot) ^ swz));
            }
        #pragma unroll
        for (int nf = 0; nf < 8; ++nf) {
            #pragma unroll
            for (int ks = 0; ks < 4; ++ks) {
                const int row = nf * 16 + lrow;
                bf16x8 bfr = *(const bf16x8*)(smem + 32768 + (((row << 8) + (ks << 6) + kslot) ^ swz));
                acc[0][nf] = __builtin_amdgcn_mfma_f32_16x16x32_bf16(afr[0][ks], bfr, acc[0][nf], 0, 0, 0);
                acc[1][nf] = __builtin_amdgcn_mfma_f32_16x16x32_bf16(afr[1][ks], bfr, acc[1][nf], 0, 0, 0);
            }
        }
    }

    // ---- re-stage h as bf16 (swizzled) + stage Wb ----
    __syncthreads();
    for (int p = tid; p < 2048; p += 256) {
        const int row = p >> 4, chunk = p & 15;
        const int off = ((row << 8) + (chunk << 4)) ^ ((row & 7) << 4);
        *(float4*)(smem + 32768 + off) = *(const float4*)(Wb + (size_t)row * FEAT + chunk * 8);
    }
    #pragma unroll
    for (int mf = 0; mf < 2; ++mf)
        #pragma unroll
        for (int nf = 0; nf < 8; ++nf)
            #pragma unroll
            for (int rg = 0; rg < 4; ++rg) {
                const int row = wm0 + mf * 16 + (lane >> 4) * 4 + rg;
                const int offb = ((row << 8) + (nf * 16 + lrow) * 2) ^ ((row & 7) << 4);
                *(unsigned short*)(smem + offb) = f2bf(acc[mf][nf][rg]);
            }
    __syncthreads();

    // ---- stage 2: K=128 ----
    f32x4 acc2[2][8];
    #pragma unroll
    for (int a = 0; a < 2; ++a)
        #pragma unroll
        for (int b = 0; b < 8; ++b) acc2[a][b] = (f32x4){0.f, 0.f, 0.f, 0.f};
    bf16x8 afr2[2][4];
    #pragma unroll
    for (int mf = 0; mf < 2; ++mf)
        #pragma unroll
        for (int ks = 0; ks < 4; ++ks) {
            const int row = wm0 + mf * 16 + lrow;
            afr2[mf][ks] = *(const bf16x8*)(smem + (((row << 8) + (ks << 6) + kslot) ^ swz));
        }
    #pragma unroll
    for (int nf = 0; nf < 8; ++nf) {
        #pragma unroll
        for (int ks = 0; ks < 4; ++ks) {
            const int row = nf * 16 + lrow;
            bf16x8 bfr = *(const bf16x8*)(smem + 32768 + (((row << 8) + (ks << 6) + kslot) ^ swz));
            acc2[0][nf] = __builtin_amdgcn_mfma_f32_16x16x32_bf16(afr2[0][ks], bfr, acc2[0][nf], 0, 0, 0);
            acc2[1][nf] = __builtin_amdgcn_mfma_f32_16x16x32_bf16(afr2[1][ks], bfr, acc2[1][nf], 0, 0, 0);
        }
    }

    // ---- epilogue: bias + ReLU + store f32 + BN column stats ----
    float s[8], s2[8], bv[8];
    #pragma unroll
    for (int nf = 0; nf < 8; ++nf) { s[nf] = 0.f; s2[nf] = 0.f; bv[nf] = bias[nf * 16 + lrow]; }
    #pragma unroll
    for (int mf = 0; mf < 2; ++mf)
        #pragma unroll
        for (int nf = 0; nf < 8; ++nf)
            #pragma unroll
            for (int rg = 0; rg < 4; ++rg) {
                const int row = m0 + wm0 + mf * 16 + (lane >> 4) * 4 + rg;
                if (row < M) {
                    const float v = fmaxf(acc2[mf][nf][rg] + bv[nf], 0.f);
                    out[(size_t)row * FEAT + nf * 16 + lrow] = v;
                    s[nf] += v;
                    s2[nf] = fmaf(v, v, s2[nf]);
                }
            }
    #pragma unroll
    for (int nf = 0; nf < 8; ++nf) {
        s[nf]  += __shfl_xor(s[nf], 16);  s[nf]  += __shfl_xor(s[nf], 32);
        s2[nf] += __shfl_xor(s2[nf], 16); s2[nf] += __shfl_xor(s2[nf], 32);
    }
    __syncthreads();
    float* red = (float*)smem;
    if (lane < 16) {
        #pragma unroll
        for (int nf = 0; nf < 8; ++nf) {
            red[wave * 256 + nf * 16 + lane]       = s[nf];
            red[wave * 256 + 128 + nf * 16 + lane] = s2[nf];
        }
    }
    __syncthreads();
    if (tid < 128) {
        const float ss = red[tid] + red[256 + tid] + red[512 + tid] + red[768 + tid];
        const float qq = red[128 + tid] + red[384 + tid] + red[640 + tid] + red[896 + tid];
        atomicAdd(sbuf + tid, ss);
        atomicAdd(sbuf + FEAT + tid, qq);
    }
}

// ---- mean/var -> scale/shift ----
__global__ void finalize(const float* __restrict__ sbuf,
                         const float* __restrict__ gamma,
                         const float* __restrict__ beta,
                         float* __restrict__ ss) {
    const int o = threadIdx.x;
    const float mean = sbuf[o] / (float)N_NODES;
    const float var  = sbuf[FEAT + o] / (float)N_NODES - mean * mean;
    const float sc   = gamma[o] * rsqrtf(var + BN_EPS);
    ss[o] = sc;
    ss[FEAT + o] = beta[o] - mean * sc;
}

// ---- out = out*scale + shift (in place, float4) ----
__global__ void normalize(float* __restrict__ y, const float* __restrict__ ss) {
    const int idx = blockIdx.x * blockDim.x + threadIdx.x;
    const int o4 = (idx & 31) * 4;
    float4 v = *(float4*)(y + (size_t)idx * 4);
    const float4 sc = *(const float4*)(ss + o4);
    const float4 sh = *(const float4*)(ss + FEAT + o4);
    v.x = fmaf(v.x, sc.x, sh.x);
    v.y = fmaf(v.y, sc.y, sh.y);
    v.z = fmaf(v.z, sc.z, sh.z);
    v.w = fmaf(v.w, sc.w, sh.w);
    *(float4*)(y + (size_t)idx * 4) = v;
}

extern "C" void kernel_launch(void* const* d_in, const int* in_sizes, int n_in,
                              void* d_out, int out_size, void* d_ws, size_t ws_size,
                              hipStream_t stream) {
    const float* feature = (const float*)d_in[0];
    const float* coords  = (const float*)d_in[1];
    const int*   src     = (const int*)d_in[2];
    const int*   dst     = (const int*)d_in[3];
    const int*   order   = (const int*)d_in[4];
    const float* linear  = (const float*)d_in[5];
    const float* attW    = (const float*)d_in[6];
    const float* mlp_w   = (const float*)d_in[7];
    const float* mlp_b   = (const float*)d_in[8];
    const float* gamma   = (const float*)d_in[9];
    const float* beta    = (const float*)d_in[10];
    float* out = (float*)d_out;

    char* p = (char*)d_ws;
    unsigned short* fb   = (unsigned short*)p; p += (size_t)N_NODES * FEAT * 2;   // 12.8 MB
    unsigned short* agg  = (unsigned short*)p; p += (size_t)N_NODES * 384 * 2;    // 38.4 MB
    unsigned short* LtT  = (unsigned short*)p; p += (size_t)FEAT * 384 * 2;       // 98 KB
    unsigned short* Wb   = (unsigned short*)p; p += (size_t)FEAT * FEAT * 2;      // 32 KB
    float4* pk           = (float4*)p;         p += (size_t)N_NODES * 32;         // 1.6 MB
    int*   sord_p        = (int*)p;            p += (size_t)E_EDGES * 4;          // 3.2 MB
    int2*  bbuf          = (int2*)p;           p += (size_t)NBUK * BCAP * 8;      // 8.0 MB
    int*   cnt           = (int*)p;            p += 200064;
    float* sbuf          = (float*)p;          p += 1024;
    int*   gcur          = (int*)p;            p += 1024;   // memset covers cnt+sbuf+gcur
    int*   rowptr        = (int*)p;            p += 200064;
    int*   cursor        = (int*)p;            p += 200064;
    int*   bsum          = (int*)p;            p += 256;
    int*   boff          = (int*)p;            p += 256;
    float* ss            = (float*)p;          p += 1024;

    hipMemsetAsync(cnt, 0, 200064 + 1024 + 1024, stream);

    const int NWB = (N_NODES * 64) / 256;         // 12500
    const int MB  = (N_NODES + 127) / 128;        // 391
    const int AB  = (E_EDGES + 2047) / 2048;      // 391

    wprep<<<FEAT, FEAT, 0, stream>>>(mlp_w, linear, Wb, LtT);
    g_cast<<<NWB, 256, 0, stream>>>(feature, coords, attW, fb, pk);

    bucketA<<<AB, 256, 0, stream>>>(src, dst, order, cnt, gcur, bbuf);
    scan1<<<NB1, 256, 0, stream>>>(cnt, rowptr, bsum);
    scan2<<<1, 64, 0, stream>>>(bsum, boff, rowptr);
    scan3<<<(N_NODES + 255) / 256, 256, 0, stream>>>(rowptr, cursor, boff);
    bucketB<<<NBUK * 8, 256, 0, stream>>>(gcur, bbuf, cursor, sord_p);

    segagg<<<NWB, 256, 0, stream>>>(pk, sord_p, rowptr, fb, agg);

    fused_gemm<<<MB, 256, 0, stream>>>(agg, LtT, Wb, out, N_NODES, mlp_b, sbuf);
    finalize<<<1, FEAT, 0, stream>>>(sbuf, gamma, beta, ss);
    normalize<<<(N_NODES * 32) / 256, 256, 0, stream>>>(out, ss);
}

// Round 9
// 191.661 us; speedup vs baseline: 8.1691x; 1.0180x over previous
//
#include <hip/hip_runtime.h>

#define N_NODES 50000
#define E_EDGES 800000
#define FEAT    128
#define KORD    3
#define BN_EPS  1e-5f
#define NB1     49          // ceil(50000/1024) scan blocks
#define NBUK    49          // coarse buckets (dst >> 10)
#define BCAP    20480       // bucket capacity

typedef __fp16 f16x2 __attribute__((ext_vector_type(2)));
typedef __fp16 f16x8 __attribute__((ext_vector_type(8)));
typedef __attribute__((ext_vector_type(4))) float f32x4;

__device__ __forceinline__ unsigned h2u(f16x2 h) { union { f16x2 h; unsigned u; } c; c.h = h; return c.u; }
__device__ __forceinline__ f16x2 u2h(unsigned u) { union { unsigned u; f16x2 h; } c; c.u = u; return c.h; }

// ---- weights prep (f16): Wb[o][i]=W[o][i];  LtT[o][k*128+i]=L[k][i][o] ----
__global__ void wprep(const float* __restrict__ W, const float* __restrict__ L,
                      __fp16* __restrict__ Wb, __fp16* __restrict__ LtT) {
    const int o = blockIdx.x;      // 128
    const int i = threadIdx.x;     // 128
    Wb[o * FEAT + i] = (__fp16)W[o * FEAT + i];
    #pragma unroll
    for (int k = 0; k < KORD; ++k)
        LtT[(size_t)o * 384 + k * FEAT + i] = (__fp16)L[((size_t)k * FEAT + i) * FEAT + o];
}

// ---- per node: feature->f16, and pack {coords, g=attW@f} into 2 float4 ----
__global__ void g_cast(const float* __restrict__ feat,
                       const float* __restrict__ coords,
                       const float* __restrict__ attW,
                       __fp16* __restrict__ fh,
                       float4* __restrict__ pk) {
    const int node = (blockIdx.x * blockDim.x + threadIdx.x) >> 6;
    const int lane = threadIdx.x & 63;
    if (node >= N_NODES) return;
    const float2 f = *(const float2*)(feat + (size_t)node * FEAT + lane * 2);
    *(f16x2*)(fh + (size_t)node * FEAT + lane * 2) = __builtin_amdgcn_cvt_pkrtz(f.x, f.y);
    float gg[3];
    #pragma unroll
    for (int j = 0; j < 3; ++j) {
        float p = f.x * attW[j * FEAT + lane * 2] + f.y * attW[j * FEAT + lane * 2 + 1];
        #pragma unroll
        for (int off = 32; off; off >>= 1) p += __shfl_xor(p, off);
        gg[j] = p;
    }
    if (lane == 0) {
        const float c0 = coords[node * 3 + 0], c1 = coords[node * 3 + 1], c2 = coords[node * 3 + 2];
        pk[2 * node]     = make_float4(c0, c1, c2, gg[0]);
        pk[2 * node + 1] = make_float4(gg[1], gg[2], 0.f, 0.f);
    }
}

// ============ CSR build ============
__global__ __launch_bounds__(256)
void bucketA(const int* __restrict__ src, const int* __restrict__ dst,
             const int* __restrict__ order,
             int* __restrict__ cnt, int* __restrict__ gcur, int2* __restrict__ bbuf) {
    __shared__ int lcnt[NBUK];
    __shared__ int lbase[NBUK];
    const int tid = threadIdx.x;
    if (tid < NBUK) lcnt[tid] = 0;
    __syncthreads();
    const int e0 = blockIdx.x * 2048;
    int b[8], r[8], so[8], dd[8];
    #pragma unroll
    for (int i = 0; i < 8; ++i) {
        const int e = e0 + i * 256 + tid;
        if (e < E_EDGES) {
            dd[i] = dst[e];
            so[i] = (order[e] << 16) | src[e];
            b[i] = dd[i] >> 10;
            r[i] = atomicAdd(&lcnt[b[i]], 1);
            atomicAdd(cnt + dd[i], 1);
        } else b[i] = -1;
    }
    __syncthreads();
    if (tid < NBUK) lbase[tid] = atomicAdd(&gcur[tid], lcnt[tid]);
    __syncthreads();
    #pragma unroll
    for (int i = 0; i < 8; ++i)
        if (b[i] >= 0)
            bbuf[(size_t)b[i] * BCAP + lbase[b[i]] + r[i]] = make_int2(so[i], dd[i]);
}

__global__ __launch_bounds__(256)
void scan1(const int* __restrict__ cnt, int* __restrict__ rowptr, int* __restrict__ bsum) {
    __shared__ int lds[256];
    const int b = blockIdx.x, t = threadIdx.x;
    const int base = b * 1024 + t * 4;
    int v[4];
    #pragma unroll
    for (int i = 0; i < 4; ++i) v[i] = (base + i < N_NODES) ? cnt[base + i] : 0;
    lds[t] = v[0] + v[1] + v[2] + v[3];
    __syncthreads();
    for (int off = 1; off < 256; off <<= 1) {
        const int u = (t >= off) ? lds[t - off] : 0;
        __syncthreads();
        lds[t] += u;
        __syncthreads();
    }
    int excl = t ? lds[t - 1] : 0;
    if (t == 255) bsum[b] = lds[255];
    #pragma unroll
    for (int i = 0; i < 4; ++i) {
        if (base + i < N_NODES) rowptr[base + i] = excl;
        excl += v[i];
    }
}

__global__ void scan2(const int* __restrict__ bsum, int* __restrict__ boff,
                      int* __restrict__ rowptr) {
    const int lane = threadIdx.x;   // 64
    const int v = (lane < NB1) ? bsum[lane] : 0;
    int incl = v;
    #pragma unroll
    for (int off = 1; off < 64; off <<= 1) {
        const int u = __shfl_up(incl, off);
        if (lane >= off) incl += u;
    }
    if (lane < NB1) boff[lane] = incl - v;
    if (lane == 0) rowptr[N_NODES] = E_EDGES;
}

__global__ void scan3(int* __restrict__ rowptr, int* __restrict__ cursor,
                      const int* __restrict__ boff) {
    const int i = blockIdx.x * blockDim.x + threadIdx.x;
    if (i >= N_NODES) return;
    const int v = rowptr[i] + boff[i >> 10];
    rowptr[i] = v;
    cursor[i] = v;
}

__global__ void bucketB(const int* __restrict__ gcur, const int2* __restrict__ bbuf,
                        int* __restrict__ cursor, int* __restrict__ sord_p) {
    const int b = blockIdx.x >> 3;
    const int seg = blockIdx.x & 7;
    const int n = gcur[b];
    const int lo = (int)((long)n * seg / 8), hi = (int)((long)n * (seg + 1) / 8);
    for (int i = lo + (int)threadIdx.x; i < hi; i += 256) {
        const int2 ent = bbuf[(size_t)b * BCAP + i];
        const int pos = atomicAdd(cursor + ent.y, 1);
        sord_p[pos] = ent.x;
    }
}

// ---- fused edge-att + segment softmax + per-order gather-aggregate ----
// agg[n][k*128+i] = sum_{e in CSR[n], order=k} w_e * f[src_e, i]   (f16 out)
// Inner loop: LDS stash (w0,w1,w2 as f16x2 masked by order, sn) -> ds_read_b128
// broadcast; pair-gather (lane halves = 2 edges); 6x v_pk_fma_f16, branch-free.
__global__ void segagg(const float4* __restrict__ pk,
                       const int* __restrict__ sord_p,
                       const int* __restrict__ rowptr,
                       const __fp16* __restrict__ fh,
                       __fp16* __restrict__ agg) {
    __shared__ uint4 stash[4][64];
    const int node = (blockIdx.x * blockDim.x + threadIdx.x) >> 6;
    const int lane = threadIdx.x & 63;
    const int wid  = threadIdx.x >> 6;
    if (node >= N_NODES) return;
    const int beg = rowptr[node], end = rowptr[node + 1];
    const float4 b0 = pk[2 * node];

    // phase 1: online (m,s); cache chunk-0 (deg<=64 covers ~all nodes)
    float att0 = -1e30f, inv0 = 0.f; int sol0 = 0;
    float m = -1e30f, s = 0.f;
    int nch = 0;
    for (int cb = beg; cb < end; cb += 64, ++nch) {
        const int p = cb + lane;
        float a = -1e30f, iv = 0.f; int so = 0;
        if (p < end) {
            so = sord_p[p];
            const int sn = so & 0xFFFF;
            const float4 a0 = pk[2 * sn], a1 = pk[2 * sn + 1];
            const float dx = a0.x - b0.x, dy = a0.y - b0.y, dz = a0.z - b0.z;
            a = dx * a0.w + dy * a1.x + dz * a1.y;
            iv = 1.f / (dx * dx + dy * dy + dz * dz + 1.f);
        }
        if (nch == 0) { att0 = a; inv0 = iv; sol0 = so; }
        const float mn = fmaxf(m, a);
        s = s * __expf(m - mn) + ((p < end) ? __expf(a - mn) : 0.f);
        m = mn;
    }
    #pragma unroll
    for (int off = 32; off; off >>= 1) {
        const float mo = __shfl_xor(m, off), so_ = __shfl_xor(s, off);
        const float mn = fmaxf(m, mo);
        s = s * __expf(m - mn) + so_ * __expf(mo - mn);
        m = mn;
    }
    const float inv_s = s > 0.f ? 1.f / s : 0.f;

    // phase 2
    const int half = lane >> 5;
    const int lsub = lane & 31;
    f16x2 acc00 = {0, 0}, acc01 = {0, 0};
    f16x2 acc10 = {0, 0}, acc11 = {0, 0};
    f16x2 acc20 = {0, 0}, acc21 = {0, 0};

    int ch = 0;
    for (int cb = beg; cb < end; cb += 64, ++ch) {
        const int p = cb + lane;
        float wl = 0.f; int so = 0;
        if (ch == 0) {
            wl = __expf(att0 - m) * inv_s * inv0;   // dead lanes: 0
            so = sol0;
        } else if (p < end) {
            so = sord_p[p];
            const int sn = so & 0xFFFF;
            const float4 a0 = pk[2 * sn], a1 = pk[2 * sn + 1];
            const float dx = a0.x - b0.x, dy = a0.y - b0.y, dz = a0.z - b0.z;
            const float a = dx * a0.w + dy * a1.x + dz * a1.y;
            wl = __expf(a - m) * inv_s / (dx * dx + dy * dy + dz * dz + 1.f);
        }
        // stash entry: per-order masked packed weight + row index
        const int k = so >> 16;
        const __fp16 wh = (__fp16)wl;
        f16x2 w2; w2.x = wh; w2.y = wh;
        const unsigned uw = h2u(w2);
        stash[wid][lane] = make_uint4(k == 0 ? uw : 0u, k == 1 ? uw : 0u,
                                      k == 2 ? uw : 0u, (unsigned)(so & 0xFFFF));
        // (wave-private region; LDS ops are in-order within a wave)
        const int ne = min(64, end - cb);
        const uint4* st = stash[wid];
        for (int t = 0; t < ne; t += 2) {
            const uint4 e = st[t + half];    // half 0: edge t, half 1: edge t+1 (zero-wt pad ok)
            const uint2 v = *(const uint2*)((const char*)fh + ((size_t)e.w << 8) + lsub * 8);
            const f16x2 va = u2h(v.x), vb = u2h(v.y);
            acc00 = __builtin_elementwise_fma(va, u2h(e.x), acc00);
            acc01 = __builtin_elementwise_fma(vb, u2h(e.x), acc01);
            acc10 = __builtin_elementwise_fma(va, u2h(e.y), acc10);
            acc11 = __builtin_elementwise_fma(vb, u2h(e.y), acc11);
            acc20 = __builtin_elementwise_fma(va, u2h(e.z), acc20);
            acc21 = __builtin_elementwise_fma(vb, u2h(e.z), acc21);
        }
    }
    // combine halves (lane l and l+32 hold the same 4 features)
    acc00 = acc00 + u2h(__shfl_xor((int)h2u(acc00), 32));
    acc01 = acc01 + u2h(__shfl_xor((int)h2u(acc01), 32));
    acc10 = acc10 + u2h(__shfl_xor((int)h2u(acc10), 32));
    acc11 = acc11 + u2h(__shfl_xor((int)h2u(acc11), 32));
    acc20 = acc20 + u2h(__shfl_xor((int)h2u(acc20), 32));
    acc21 = acc21 + u2h(__shfl_xor((int)h2u(acc21), 32));
    if (lane < 32) {
        __fp16* row = agg + (size_t)node * 384 + lsub * 4;
        *(uint2*)(row)       = make_uint2(h2u(acc00), h2u(acc01));
        *(uint2*)(row + 128) = make_uint2(h2u(acc10), h2u(acc11));
        *(uint2*)(row + 256) = make_uint2(h2u(acc20), h2u(acc21));
    }
}

// ============================================================================
// Fused two-stage MFMA GEMM (f16):
//   stage 1: h[m,o] = sum_{ki<384} agg[m,ki] * LtT[o,ki]     (K=384)
//   stage 2: y[m,o] = relu(sum_i f16(h)[m,i] * Wb[o,i] + b)  (K=128) + BN stats
// ============================================================================
__global__ __launch_bounds__(256)
void fused_gemm(const unsigned short* __restrict__ agg,
                const unsigned short* __restrict__ LtT,
                const unsigned short* __restrict__ Wb,
                float* __restrict__ out, int M,
                const float* __restrict__ bias, float* __restrict__ sbuf) {
    __shared__ char smem[65536];
    const int m0 = blockIdx.x * 128;
    const int tid = threadIdx.x;
    const int wave = tid >> 6, lane = tid & 63;
    const int wm0 = wave * 32;
    const int lrow = lane & 15;
    const int kslot = (lane >> 4) << 4;
    const int swz = (lrow & 7) << 4;

    f32x4 acc[2][8];
    #pragma unroll
    for (int a = 0; a < 2; ++a)
        #pragma unroll
        for (int b = 0; b < 8; ++b) acc[a][b] = (f32x4){0.f, 0.f, 0.f, 0.f};

    // ---- stage 1: K=384 in three 128-chunks ----
    for (int kc = 0; kc < 3; ++kc) {
        __syncthreads();
        for (int p = tid; p < 2048; p += 256) {
            const int row = p >> 4, chunk = p & 15;
            const int off = ((row << 8) + (chunk << 4)) ^ ((row & 7) << 4);
            float4 va = make_float4(0.f, 0.f, 0.f, 0.f);
            if (m0 + row < M)
                va = *(const float4*)(agg + (size_t)(m0 + row) * 384 + kc * 128 + chunk * 8);
            *(float4*)(smem + off) = va;
            *(float4*)(smem + 32768 + off) =
                *(const float4*)(LtT + (size_t)row * 384 + kc * 128 + chunk * 8);
        }
        __syncthreads();
        f16x8 afr[2][4];
        #pragma unroll
        for (int mf = 0; mf < 2; ++mf)
            #pragma unroll
            for (int ks = 0; ks < 4; ++ks) {
                const int row = wm0 + mf * 16 + lrow;
                afr[mf][ks] = *(const f16x8*)(smem + (((row << 8) + (ks << 6) + kslot) ^ swz));
            }
        #pragma unroll
        for (int nf = 0; nf < 8; ++nf) {
            #pragma unroll
            for (int ks = 0; ks < 4; ++ks) {
                const int row = nf * 16 + lrow;
                f16x8 bfr = *(const f16x8*)(smem + 32768 + (((row << 8) + (ks << 6) + kslot) ^ swz));
                acc[0][nf] = __builtin_amdgcn_mfma_f32_16x16x32_f16(afr[0][ks], bfr, acc[0][nf], 0, 0, 0);
                acc[1][nf] = __builtin_amdgcn_mfma_f32_16x16x32_f16(afr[1][ks], bfr, acc[1][nf], 0, 0, 0);
            }
        }
    }

    // ---- re-stage h as f16 (swizzled) + stage Wb ----
    __syncthreads();
    for (int p = tid; p < 2048; p += 256) {
        const int row = p >> 4, chunk = p & 15;
        const int off = ((row << 8) + (chunk << 4)) ^ ((row & 7) << 4);
        *(float4*)(smem + 32768 + off) = *(const float4*)(Wb + (size_t)row * FEAT + chunk * 8);
    }
    #pragma unroll
    for (int mf = 0; mf < 2; ++mf)
        #pragma unroll
        for (int nf = 0; nf < 8; ++nf)
            #pragma unroll
            for (int rg = 0; rg < 4; ++rg) {
                const int row = wm0 + mf * 16 + (lane >> 4) * 4 + rg;
                const int offb = ((row << 8) + (nf * 16 + lrow) * 2) ^ ((row & 7) << 4);
                *(__fp16*)(smem + offb) = (__fp16)acc[mf][nf][rg];
            }
    __syncthreads();

    // ---- stage 2: K=128 ----
    f32x4 acc2[2][8];
    #pragma unroll
    for (int a = 0; a < 2; ++a)
        #pragma unroll
        for (int b = 0; b < 8; ++b) acc2[a][b] = (f32x4){0.f, 0.f, 0.f, 0.f};
    f16x8 afr2[2][4];
    #pragma unroll
    for (int mf = 0; mf < 2; ++mf)
        #pragma unroll
        for (int ks = 0; ks < 4; ++ks) {
            const int row = wm0 + mf * 16 + lrow;
            afr2[mf][ks] = *(const f16x8*)(smem + (((row << 8) + (ks << 6) + kslot) ^ swz));
        }
    #pragma unroll
    for (int nf = 0; nf < 8; ++nf) {
        #pragma unroll
        for (int ks = 0; ks < 4; ++ks) {
            const int row = nf * 16 + lrow;
            f16x8 bfr = *(const f16x8*)(smem + 32768 + (((row << 8) + (ks << 6) + kslot) ^ swz));
            acc2[0][nf] = __builtin_amdgcn_mfma_f32_16x16x32_f16(afr2[0][ks], bfr, acc2[0][nf], 0, 0, 0);
            acc2[1][nf] = __builtin_amdgcn_mfma_f32_16x16x32_f16(afr2[1][ks], bfr, acc2[1][nf], 0, 0, 0);
        }
    }

    // ---- epilogue: bias + ReLU + store f32 + BN column stats ----
    float s[8], s2[8], bv[8];
    #pragma unroll
    for (int nf = 0; nf < 8; ++nf) { s[nf] = 0.f; s2[nf] = 0.f; bv[nf] = bias[nf * 16 + lrow]; }
    #pragma unroll
    for (int mf = 0; mf < 2; ++mf)
        #pragma unroll
        for (int nf = 0; nf < 8; ++nf)
            #pragma unroll
            for (int rg = 0; rg < 4; ++rg) {
                const int row = m0 + wm0 + mf * 16 + (lane >> 4) * 4 + rg;
                if (row < M) {
                    const float v = fmaxf(acc2[mf][nf][rg] + bv[nf], 0.f);
                    out[(size_t)row * FEAT + nf * 16 + lrow] = v;
                    s[nf] += v;
                    s2[nf] = fmaf(v, v, s2[nf]);
                }
            }
    #pragma unroll
    for (int nf = 0; nf < 8; ++nf) {
        s[nf]  += __shfl_xor(s[nf], 16);  s[nf]  += __shfl_xor(s[nf], 32);
        s2[nf] += __shfl_xor(s2[nf], 16); s2[nf] += __shfl_xor(s2[nf], 32);
    }
    __syncthreads();
    float* red = (float*)smem;
    if (lane < 16) {
        #pragma unroll
        for (int nf = 0; nf < 8; ++nf) {
            red[wave * 256 + nf * 16 + lane]       = s[nf];
            red[wave * 256 + 128 + nf * 16 + lane] = s2[nf];
        }
    }
    __syncthreads();
    if (tid < 128) {
        const float ss = red[tid] + red[256 + tid] + red[512 + tid] + red[768 + tid];
        const float qq = red[128 + tid] + red[384 + tid] + red[640 + tid] + red[896 + tid];
        atomicAdd(sbuf + tid, ss);
        atomicAdd(sbuf + FEAT + tid, qq);
    }
}

// ---- BN normalize (finalize fused:每 block derives scale/shift from sbuf) ----
__global__ void normalize(float* __restrict__ y, const float* __restrict__ sbuf,
                          const float* __restrict__ gamma, const float* __restrict__ beta) {
    __shared__ float sc_s[FEAT], sh_s[FEAT];
    const int t = threadIdx.x;
    if (t < FEAT) {
        const float mean = sbuf[t] / (float)N_NODES;
        const float var  = sbuf[FEAT + t] / (float)N_NODES - mean * mean;
        const float sc   = gamma[t] * rsqrtf(var + BN_EPS);
        sc_s[t] = sc;
        sh_s[t] = beta[t] - mean * sc;
    }
    __syncthreads();
    const int idx = blockIdx.x * blockDim.x + t;
    const int o4 = (idx & 31) * 4;
    float4 v = *(float4*)(y + (size_t)idx * 4);
    const float4 sc = *(const float4*)(sc_s + o4);
    const float4 sh = *(const float4*)(sh_s + o4);
    v.x = fmaf(v.x, sc.x, sh.x);
    v.y = fmaf(v.y, sc.y, sh.y);
    v.z = fmaf(v.z, sc.z, sh.z);
    v.w = fmaf(v.w, sc.w, sh.w);
    *(float4*)(y + (size_t)idx * 4) = v;
}

extern "C" void kernel_launch(void* const* d_in, const int* in_sizes, int n_in,
                              void* d_out, int out_size, void* d_ws, size_t ws_size,
                              hipStream_t stream) {
    const float* feature = (const float*)d_in[0];
    const float* coords  = (const float*)d_in[1];
    const int*   src     = (const int*)d_in[2];
    const int*   dst     = (const int*)d_in[3];
    const int*   order   = (const int*)d_in[4];
    const float* linear  = (const float*)d_in[5];
    const float* attW    = (const float*)d_in[6];
    const float* mlp_w   = (const float*)d_in[7];
    const float* mlp_b   = (const float*)d_in[8];
    const float* gamma   = (const float*)d_in[9];
    const float* beta    = (const float*)d_in[10];
    float* out = (float*)d_out;

    char* p = (char*)d_ws;
    __fp16* fh           = (__fp16*)p;  p += (size_t)N_NODES * FEAT * 2;   // 12.8 MB
    __fp16* agg          = (__fp16*)p;  p += (size_t)N_NODES * 384 * 2;    // 38.4 MB
    __fp16* LtT          = (__fp16*)p;  p += (size_t)FEAT * 384 * 2;       // 98 KB
    __fp16* Wb           = (__fp16*)p;  p += (size_t)FEAT * FEAT * 2;      // 32 KB
    float4* pk           = (float4*)p;  p += (size_t)N_NODES * 32;         // 1.6 MB
    int*   sord_p        = (int*)p;     p += (size_t)E_EDGES * 4;          // 3.2 MB
    int2*  bbuf          = (int2*)p;    p += (size_t)NBUK * BCAP * 8;      // 8.0 MB
    int*   cnt           = (int*)p;     p += 200064;
    float* sbuf          = (float*)p;   p += 1024;
    int*   gcur          = (int*)p;     p += 1024;   // memset covers cnt+sbuf+gcur
    int*   rowptr        = (int*)p;     p += 200064;
    int*   cursor        = (int*)p;     p += 200064;
    int*   bsum          = (int*)p;     p += 256;
    int*   boff          = (int*)p;     p += 256;

    hipMemsetAsync(cnt, 0, 200064 + 1024 + 1024, stream);

    const int NWB = (N_NODES * 64) / 256;         // 12500
    const int MB  = (N_NODES + 127) / 128;        // 391
    const int AB  = (E_EDGES + 2047) / 2048;      // 391

    wprep<<<FEAT, FEAT, 0, stream>>>(mlp_w, linear, Wb, LtT);
    g_cast<<<NWB, 256, 0, stream>>>(feature, coords, attW, fh, pk);

    bucketA<<<AB, 256, 0, stream>>>(src, dst, order, cnt, gcur, bbuf);
    scan1<<<NB1, 256, 0, stream>>>(cnt, rowptr, bsum);
    scan2<<<1, 64, 0, stream>>>(bsum, boff, rowptr);
    scan3<<<(N_NODES + 255) / 256, 256, 0, stream>>>(rowptr, cursor, boff);
    bucketB<<<NBUK * 8, 256, 0, stream>>>(gcur, bbuf, cursor, sord_p);

    segagg<<<NWB, 256, 0, stream>>>(pk, sord_p, rowptr, fh, agg);

    fused_gemm<<<MB, 256, 0, stream>>>((const unsigned short*)agg, (const unsigned short*)LtT,
                                       (const unsigned short*)Wb, out, N_NODES, mlp_b, sbuf);
    normalize<<<(N_NODES * 32) / 256, 256, 0, stream>>>(out, sbuf, gamma, beta);
}